// Round 10
// baseline (865.421 us; speedup 1.0000x reference)
//
#include <hip/hip_runtime.h>
#include <hip/hip_bf16.h>
#include <math.h>

#define BDIM 8
#define HH 128
#define WW 128
#define LL (HH*WW)          // 16384
#define CC 192
#define CBh 96
#define HBn 4
#define HDd 24
#define PD 6
#define RTAB 217            // (2*4-1)*(2*16-1) for both branches

typedef unsigned short ushortT;
typedef __bf16 bf16x8 __attribute__((ext_vector_type(8)));
typedef float f32x4 __attribute__((ext_vector_type(4)));

__device__ __forceinline__ float b2f(ushortT u){
  union { float f; unsigned u; } x; x.u = ((unsigned)u) << 16; return x.f;
}
__device__ __forceinline__ ushortT f2b(float f){
  union { float f; unsigned u; } x; x.f = f;
  unsigned r = x.u + 0x7fffu + ((x.u >> 16) & 1u);
  return (ushortT)(r >> 16);
}
__device__ __forceinline__ float lo16(unsigned u){ union { float f; unsigned u; } x; x.u = u << 16; return x.f; }
__device__ __forceinline__ float hi16(unsigned u){ union { float f; unsigned u; } x; x.u = u & 0xffff0000u; return x.f; }
__device__ __forceinline__ unsigned pack2(float a, float b){
  return (unsigned)f2b(a) | ((unsigned)f2b(b) << 16);
}
__device__ __forceinline__ void unpack8(uint4 u, float* f){
  f[0]=lo16(u.x); f[1]=hi16(u.x); f[2]=lo16(u.y); f[3]=hi16(u.y);
  f[4]=lo16(u.z); f[5]=hi16(u.z); f[6]=lo16(u.w); f[7]=hi16(u.w);
}
// v_cvt_pk_bf16_f32 via HIP intrinsic (RNE)
__device__ __forceinline__ unsigned cvt2(float a, float b){
  __hip_bfloat162 h = __float22bfloat162_rn(float2{a, b});
  union { __hip_bfloat162 h; unsigned u; } c; c.h = h; return c.u;
}
__device__ __forceinline__ float gelu_exact(float x){
  return 0.5f * x * (1.0f + erff(x * 0.70710678118654752f));
}

union ABu { unsigned u[4]; bf16x8 v; };

// ---- LDS weight staging: full 192x192 bf16 slice (73728 B), XOR-swizzled ----
// byte ^= ((row&7)<<4): consecutive lanes hit consecutive 16B slots (measured
// 0 conflicts in r6/r8; the 64B-stride variant measured 3.5M — keep THIS layout).
__device__ __forceinline__ void stage_B512(const ushortT* __restrict__ Wsrc, char* lds){
  int t = threadIdx.x;
  #pragma unroll
  for (int i = 0; i < 9; i++){
    int c = t + i*512;                 // 16B-chunk index, 4608 total
    int n = c / 24, kc = c - n*24;     // row, chunk-in-row
    uint4 v = *(const uint4*)(const void*)(Wsrc + n*CC + kc*8);
    int byte = n*384 + kc*16;
    byte ^= ((n & 7) << 4);
    *(uint4*)(lds + byte) = v;
  }
}
__device__ __forceinline__ bf16x8 ldsB(const char* lds, int row, int kbyte){
  int byte = row*384 + kbyte;
  byte ^= ((row & 7) << 4);
  return *(const bf16x8*)(lds + byte);
}

// ---------------- K0: dynamic position-bias MLP -> pos[2][217][4] ----------------
__device__ __forceinline__ void ln_relu6(float* p, const float* g, const float* b){
  float m = 0.f;
  #pragma unroll
  for (int j=0;j<PD;j++) m += p[j];
  m *= (1.0f/PD);
  float v = 0.f;
  #pragma unroll
  for (int j=0;j<PD;j++){ float d = p[j]-m; v += d*d; }
  v *= (1.0f/PD);
  float is = rsqrtf(v + 1e-5f);
  #pragma unroll
  for (int j=0;j<PD;j++){ float t = (p[j]-m)*is*g[j] + b[j]; p[j] = t > 0.f ? t : 0.f; }
}
__device__ __forceinline__ void mm6(float* p, const float* w, const float* c){
  float q[PD];
  #pragma unroll
  for (int j=0;j<PD;j++){
    float a = c[j];
    #pragma unroll
    for (int i=0;i<PD;i++) a += p[i]*w[j*PD+i];
    q[j] = a;
  }
  #pragma unroll
  for (int j=0;j<PD;j++) p[j] = q[j];
}

__global__ void k_pos(const float* __restrict__ pw, const float* __restrict__ pb,
                      const float* __restrict__ g1, const float* __restrict__ b1,
                      const float* __restrict__ w1, const float* __restrict__ c1,
                      const float* __restrict__ g2, const float* __restrict__ b2,
                      const float* __restrict__ w2, const float* __restrict__ c2,
                      const float* __restrict__ g3, const float* __restrict__ b3,
                      const float* __restrict__ w3, const float* __restrict__ c3,
                      float* __restrict__ pos){
  int br = blockIdx.x;
  int r = threadIdx.x;
  if (r >= RTAB) return;
  int Hsp = br ? 16 : 4, Wsp = br ? 4 : 16;
  int W2 = 2*Wsp - 1;
  float bi0 = (float)(r / W2 - (Hsp-1));
  float bi1 = (float)(r % W2 - (Wsp-1));
  const float* PW = pw + br*PD*2;
  const float* PB = pb + br*PD;
  float p[PD];
  #pragma unroll
  for (int j=0;j<PD;j++) p[j] = PW[j*2]*bi0 + PW[j*2+1]*bi1 + PB[j];
  ln_relu6(p, g1+br*PD, b1+br*PD);
  mm6(p, w1+br*PD*PD, c1+br*PD);
  ln_relu6(p, g2+br*PD, b2+br*PD);
  mm6(p, w2+br*PD*PD, c2+br*PD);
  ln_relu6(p, g3+br*PD, b3+br*PD);
  const float* W3 = w3 + br*HBn*PD;
  const float* C3 = c3 + br*HBn;
  #pragma unroll
  for (int h=0;h<HBn;h++){
    float a = C3[h];
    #pragma unroll
    for (int i=0;i<PD;i++) a += p[i]*W3[h*PD+i];
    pos[((size_t)br*RTAB + r)*HBn + h] = a;
  }
}

// ---------------- K-cvt: convert weights to bf16; fold BN params; build conv tables ----------------
#define WQKV_ELEMS (3*CC*CC)                     // 110592
#define WPROJ_ELEMS (CC*CC)                      // 36864
#define WSI_ELEMS (CC*CBh)                       // 18432
#define WALL_PAIRS ((WQKV_ELEMS+WPROJ_ELEMS+WSI_ELEMS)/2)  // 82944

__global__ void k_cvtw(const float* __restrict__ qkv_w, const float* __restrict__ proj_w,
                       const float* __restrict__ si_w1,
                       const float* __restrict__ si_b1,
                       const float* __restrict__ g, const float* __restrict__ bb,
                       const float* __restrict__ mn, const float* __restrict__ vv,
                       const float* __restrict__ si_w2,
                       const float* __restrict__ dw_w, const float* __restrict__ dw_b,
                       const float* __restrict__ bn1_g, const float* __restrict__ bn1_b,
                       const float* __restrict__ bn1_m, const float* __restrict__ bn1_v,
                       ushortT* __restrict__ wb, float* __restrict__ gparam,
                       float* __restrict__ cparam, ushortT* __restrict__ dwt){
  int t = threadIdx.x;
  if (blockIdx.x == 0 && t < CBh){
    float sc = g[t]*rsqrtf(vv[t]+1e-5f);
    gparam[t]        = sc;                                   // scale
    gparam[CBh+t]    = (si_b1[t]-mn[t])*sc + bb[t];          // folded bias
    gparam[2*CBh+t]  = si_w2[t];                             // w2
  }
  if (blockIdx.x == 1){
    if (t < CC){
      float sc = bn1_g[t]*rsqrtf(bn1_v[t]+1e-5f);
      cparam[t]      = sc;
      cparam[CC+t]   = (dw_b[t]-bn1_m[t])*sc + bn1_b[t];
    }
    for (int i = t; i < 9*CC; i += 256){
      int k = i / CC, c = i - k*CC;
      dwt[i] = f2b(dw_w[c*9 + k]);
    }
  }
  int i = blockIdx.x*256 + t;
  if (i >= WALL_PAIRS) return;
  int e = i*2;
  float a, b;
  if (e < WQKV_ELEMS){ a = qkv_w[e]; b = qkv_w[e+1]; }
  else if (e < WQKV_ELEMS+WPROJ_ELEMS){ a = proj_w[e-WQKV_ELEMS]; b = proj_w[e-WQKV_ELEMS+1]; }
  else { a = si_w1[e-WQKV_ELEMS-WPROJ_ELEMS]; b = si_w1[e-WQKV_ELEMS-WPROJ_ELEMS+1]; }
  *(unsigned*)(void*)(wb + e) = cvt2(a, b);
}

// ---------------- K1: QKV GEMM via MFMA, whole B in LDS, row-loop + full A hoist ----------------
// Grid (256,3); block 512 thr = 8 waves of 16 rows; 4 row-tiles of 128 rows per block.
// Per tile each thread issues all 12 A float4 loads up front (48 VGPR buffer).
__global__ __launch_bounds__(512, 4) void k_qkv(const float* __restrict__ x1, const float* __restrict__ x2,
                                                const ushortT* __restrict__ wb,
                                                ushortT* __restrict__ q1, ushortT* __restrict__ k2,
                                                ushortT* __restrict__ v1){
  __shared__ char Bs[CC*CC*2];     // 73728 B
  int z = blockIdx.y;
  const float* src = (z == 1) ? x2 : x1;
  ushortT* dst = (z == 0) ? q1 : ((z == 1) ? k2 : v1);
  stage_B512(wb + (size_t)z*CC*CC, Bs);
  __syncthreads();

  int w = threadIdx.x >> 6, l = threadIdx.x & 63;
  int lr = l & 15;            // frag row (A) / col (B)
  int hk = l >> 4;            // k-phase
  int crow = hk*4, ccol = lr;

  for (int it = 0; it < 4; it++){
    int row0 = (blockIdx.x*4 + it)*128 + w*16;
    const float* ap = src + (size_t)(row0 + lr)*CC + hk*8;
    // issue all 12 independent 16B loads for this thread's A row slice
    float4 buf[12];
    #pragma unroll
    for (int ks = 0; ks < 6; ks++){
      buf[ks*2+0] = *(const float4*)(ap + ks*32);
      buf[ks*2+1] = *(const float4*)(ap + ks*32 + 4);
    }
    f32x4 acc[12];
    #pragma unroll
    for (int n=0; n<12; n++) acc[n] = (f32x4){0.f,0.f,0.f,0.f};
    #pragma unroll
    for (int ks = 0; ks < 6; ks++){
      float4 p0 = buf[ks*2+0], p1 = buf[ks*2+1];
      ABu a;
      a.u[0] = cvt2(p0.x, p0.y); a.u[1] = cvt2(p0.z, p0.w);
      a.u[2] = cvt2(p1.x, p1.y); a.u[3] = cvt2(p1.z, p1.w);
      int kb = ks*64 + hk*16;
      #pragma unroll
      for (int n=0; n<12; n++){
        bf16x8 bfr = ldsB(Bs, n*16 + lr, kb);
        acc[n] = __builtin_amdgcn_mfma_f32_16x16x32_bf16(a.v, bfr, acc[n], 0, 0, 0);
      }
    }
    #pragma unroll
    for (int n=0; n<12; n++)
      #pragma unroll
      for (int r=0; r<4; r++){
        int m = row0 + crow + r;
        dst[(size_t)m*CC + n*16 + ccol] = f2b(acc[n][r]);
      }
  }
}

// ---------------- K2: windowed attention (one branch per template) ----------------
template<int HSP, int WSP>
__global__ __launch_bounds__(256) void k_attn(const ushortT* __restrict__ q1, const ushortT* __restrict__ k2,
                                              const ushortT* __restrict__ v1, const float* __restrict__ pos,
                                              ushortT* __restrict__ att){
  constexpr int BR = (HSP == 4) ? 0 : 1;
  constexpr int NWH = HH / HSP, NWW = WW / WSP;
  constexpr int CH0 = BR * CBh;
  __shared__ float ks[64][CBh];
  __shared__ float vs[64][CBh];
  __shared__ float ps[RTAB*HBn];
  int t = threadIdx.x;
  int wid = blockIdx.x;
  int b = wid / (NWH*NWW);
  int rem = wid - b*(NWH*NWW);
  int hi = rem / NWW, wj = rem - hi*NWW;
  for (int i = t; i < RTAB*HBn; i += 256) ps[i] = pos[(size_t)BR*RTAB*HBn + i];
  #pragma unroll
  for (int r = 0; r < 3; r++){
    int idx = t + r*256;        // < 768 = 64 pix * 12 segs
    int pix = idx / 12, seg = idx - pix*12;
    int ii = pix / WSP, jj = pix - ii*WSP;
    size_t base = (((size_t)b*LL) + (size_t)(hi*HSP+ii)*WW + wj*WSP + jj)*CC + CH0 + seg*8;
    uint4 uk = *(const uint4*)(const void*)(k2 + base);
    unpack8(uk, &ks[pix][seg*8]);
    uint4 uv = *(const uint4*)(const void*)(v1 + base);
    unpack8(uv, &vs[pix][seg*8]);
  }
  __syncthreads();
  int h = t >> 6, lane = t & 63;
  int i1 = lane / WSP, j1 = lane - i1*WSP;
  size_t lq = ((size_t)b*LL) + (size_t)(hi*HSP+i1)*WW + wj*WSP + j1;
  const ushortT* qrow = q1 + lq*CC + CH0 + h*HDd;
  float qf[HDd];
  #pragma unroll
  for (int d0 = 0; d0 < HDd; d0 += 8){
    uint4 u = *(const uint4*)(const void*)(qrow + d0);
    unpack8(u, &qf[d0]);
  }
  #pragma unroll
  for (int d=0; d<HDd; d++) qf[d] *= 0.20412414523193154f;   // 1/sqrt(24)
  float lg[64];
  #pragma unroll
  for (int m = 0; m < 64; m++){
    const float* kr = &ks[m][h*HDd];
    float s = 0.f;
    #pragma unroll
    for (int d=0; d<HDd; d++) s = fmaf(qf[d], kr[d], s);
    int i2 = m / WSP, j2 = m - i2*WSP;
    int ridx = (i1-i2+HSP-1)*(2*WSP-1) + (j1-j2+WSP-1);
    lg[m] = s + ps[ridx*HBn + h];
  }
  float mx = lg[0];
  #pragma unroll
  for (int m=1;m<64;m++) mx = fmaxf(mx, lg[m]);
  float sum = 0.f;
  #pragma unroll
  for (int m=0;m<64;m++){ lg[m] = __expf(lg[m]-mx); sum += lg[m]; }
  float inv = 1.0f / sum;
  float z[HDd];
  #pragma unroll
  for (int d=0;d<HDd;d++) z[d] = 0.f;
  #pragma unroll
  for (int m=0;m<64;m++){
    float p = lg[m]*inv;
    const float* vr = &vs[m][h*HDd];
    #pragma unroll
    for (int d=0;d<HDd;d++) z[d] = fmaf(p, vr[d], z[d]);
  }
  ushortT* orow = att + lq*CC + CH0 + h*HDd;
  #pragma unroll
  for (int d0=0; d0<HDd; d0+=8){
    uint4 u;
    u.x = pack2(z[d0+0], z[d0+1]);
    u.y = pack2(z[d0+2], z[d0+3]);
    u.z = pack2(z[d0+4], z[d0+5]);
    u.w = pack2(z[d0+6], z[d0+7]);
    *(uint4*)(void*)(orow + d0) = u;
  }
}

// ---------------- K3: depthwise 3x3 conv + BN + GELU, 8 channels/thread ----------------
__global__ __launch_bounds__(256) void k_conv(const ushortT* __restrict__ v1,
                                              const ushortT* __restrict__ dwt,
                                              const float* __restrict__ cparam,
                                              ushortT* __restrict__ cx){
  int tid = blockIdx.x*256 + threadIdx.x;     // SZ/8 total
  int grp = tid % 24;
  int pix = tid / 24;
  int j = pix & (WW-1);
  int rest = pix >> 7;
  int i = rest & (HH-1);
  int b = rest >> 7;
  int c0 = grp*8;
  uint4 wreg[9];
  #pragma unroll
  for (int k=0;k<9;k++) wreg[k] = *(const uint4*)(const void*)(dwt + k*CC + c0);
  float acc[8];
  #pragma unroll
  for (int t2=0;t2<8;t2++) acc[t2]=0.f;
  #pragma unroll
  for (int ki=0;ki<3;ki++){
    int ii = i + ki - 1;
    if (ii < 0 || ii >= HH) continue;
    #pragma unroll
    for (int kj=0;kj<3;kj++){
      int jj = j + kj - 1;
      if (jj < 0 || jj >= WW) continue;
      uint4 uv = *(const uint4*)(const void*)(v1 + (((size_t)b*LL) + (size_t)ii*WW + jj)*CC + c0);
      float fv[8], fw[8];
      unpack8(uv, fv);
      unpack8(wreg[ki*3+kj], fw);
      #pragma unroll
      for (int t2=0;t2<8;t2++) acc[t2] = fmaf(fv[t2], fw[t2], acc[t2]);
    }
  }
  float4 s0 = *(const float4*)(cparam + c0);
  float4 s1 = *(const float4*)(cparam + c0 + 4);
  float4 o0 = *(const float4*)(cparam + CC + c0);
  float4 o1 = *(const float4*)(cparam + CC + c0 + 4);
  float scv[8] = {s0.x,s0.y,s0.z,s0.w,s1.x,s1.y,s1.z,s1.w};
  float ofv[8] = {o0.x,o0.y,o0.z,o0.w,o1.x,o1.y,o1.z,o1.w};
  unsigned ou[4];
  #pragma unroll
  for (int t2=0;t2<4;t2++){
    float y0 = gelu_exact(acc[2*t2]  *scv[2*t2]   + ofv[2*t2]);
    float y1 = gelu_exact(acc[2*t2+1]*scv[2*t2+1] + ofv[2*t2+1]);
    ou[t2] = pack2(y0, y1);
  }
  uint4 res; res.x=ou[0]; res.y=ou[1]; res.z=ou[2]; res.w=ou[3];
  *(uint4*)(void*)(cx + (size_t)pix*CC + c0) = res;
}

// ---------------- K4: per-pixel SE gate via MFMA ----------------
__global__ __launch_bounds__(256) void k_gate(const ushortT* __restrict__ att,
                                              const ushortT* __restrict__ wsi,
                                              const float* __restrict__ gparam,
                                              const float* __restrict__ si_b2,
                                              float* __restrict__ gate){
  int w = threadIdx.x >> 6, l = threadIdx.x & 63;
  int row0 = blockIdx.x*128 + w*32;
  int lr = l & 15;
  int lk = (l >> 4) * 8;
  f32x4 acc[2][6];
  #pragma unroll
  for (int rt=0; rt<2; rt++)
    #pragma unroll
    for (int n=0; n<6; n++) acc[rt][n] = (f32x4){0.f,0.f,0.f,0.f};
  #pragma unroll
  for (int ks = 0; ks < 6; ks++){
    int k0 = ks*32 + lk;
    bf16x8 a0 = *(const bf16x8*)(const void*)(att + (size_t)(row0 + lr)*CC + k0);
    bf16x8 a1 = *(const bf16x8*)(const void*)(att + (size_t)(row0 + 16 + lr)*CC + k0);
    #pragma unroll
    for (int n=0; n<6; n++){
      bf16x8 bfr = *(const bf16x8*)(const void*)(wsi + (size_t)(n*16 + lr)*CC + k0);
      acc[0][n] = __builtin_amdgcn_mfma_f32_16x16x32_bf16(a0, bfr, acc[0][n], 0, 0, 0);
      acc[1][n] = __builtin_amdgcn_mfma_f32_16x16x32_bf16(a1, bfr, acc[1][n], 0, 0, 0);
    }
  }
  int crow = (l >> 4) * 4, ccol = l & 15;
  float sc6[6], cb6[6], w26[6];
  #pragma unroll
  for (int n=0; n<6; n++){
    int o = n*16 + ccol;
    sc6[n] = gparam[o];
    cb6[n] = gparam[CBh + o];
    w26[n] = gparam[2*CBh + o];
  }
  float sb2 = si_b2[0];
  float ps[2][4];
  #pragma unroll
  for (int rt=0; rt<2; rt++)
    #pragma unroll
    for (int r=0; r<4; r++) ps[rt][r] = 0.f;
  #pragma unroll
  for (int rt=0; rt<2; rt++)
    #pragma unroll
    for (int n=0; n<6; n++)
      #pragma unroll
      for (int r=0; r<4; r++){
        float x = acc[rt][n][r]*sc6[n] + cb6[n];
        ps[rt][r] += gelu_exact(x) * w26[n];
      }
  #pragma unroll
  for (int rt=0; rt<2; rt++)
    #pragma unroll
    for (int r=0; r<4; r++){
      float v = ps[rt][r];
      #pragma unroll
      for (int off = 1; off < 16; off <<= 1) v += __shfl_xor(v, off, 64);
      ps[rt][r] = v;
    }
  if (ccol == 0){
    #pragma unroll
    for (int rt=0; rt<2; rt++)
      #pragma unroll
      for (int r=0; r<4; r++){
        int m = row0 + rt*16 + crow + r;
        gate[m] = 1.0f / (1.0f + __expf(-(ps[rt][r] + sb2)));
      }
  }
}

// ---------------- K5: proj GEMM via MFMA, whole B in LDS, row-loop, fused gate ----------------
// Grid 256; block 512 thr = 8 waves of 16 rows; 4 row-tiles of 128 rows per block.
__global__ __launch_bounds__(512, 4) void k_proj(const ushortT* __restrict__ att, const ushortT* __restrict__ cx,
                                                 const float* __restrict__ gate,
                                                 const ushortT* __restrict__ wp, const float* __restrict__ pbias,
                                                 float* __restrict__ out){
  __shared__ char Bs[CC*CC*2];     // 73728 B
  stage_B512(wp, Bs);
  __syncthreads();

  int w = threadIdx.x >> 6, l = threadIdx.x & 63;
  int lr = l & 15;
  int hk = l >> 4;
  int crow = hk*4, ccol = lr;

  for (int it = 0; it < 4; it++){
    int row0 = (blockIdx.x*4 + it)*128 + w*16;
    float gv = gate[row0 + lr];
    size_t base = (size_t)(row0 + lr)*CC + hk*8;
    // issue all 12 independent 16B loads (6 att + 6 cx) up front
    uint4 ba[6], bc[6];
    #pragma unroll
    for (int ks = 0; ks < 6; ks++){
      ba[ks] = *(const uint4*)(const void*)(att + base + ks*32);
      bc[ks] = *(const uint4*)(const void*)(cx  + base + ks*32);
    }
    f32x4 acc[12];
    #pragma unroll
    for (int n=0; n<12; n++) acc[n] = (f32x4){0.f,0.f,0.f,0.f};
    #pragma unroll
    for (int ks = 0; ks < 6; ks++){
      float fa[8], fc[8];
      unpack8(ba[ks], fa); unpack8(bc[ks], fc);
      #pragma unroll
      for (int j=0;j<8;j++) fa[j] = fmaf(gv, fc[j], fa[j]);
      ABu a;
      a.u[0] = cvt2(fa[0], fa[1]); a.u[1] = cvt2(fa[2], fa[3]);
      a.u[2] = cvt2(fa[4], fa[5]); a.u[3] = cvt2(fa[6], fa[7]);
      int kb = ks*64 + hk*16;
      #pragma unroll
      for (int n=0; n<12; n++){
        bf16x8 bfr = ldsB(Bs, n*16 + lr, kb);
        acc[n] = __builtin_amdgcn_mfma_f32_16x16x32_bf16(a.v, bfr, acc[n], 0, 0, 0);
      }
    }
    #pragma unroll
    for (int n=0; n<12; n++){
      float bv = pbias[n*16 + ccol];
      #pragma unroll
      for (int r=0; r<4; r++){
        int m = row0 + crow + r;
        out[(size_t)m*CC + n*16 + ccol] = acc[n][r] + bv;
      }
    }
  }
}

extern "C" void kernel_launch(void* const* d_in, const int* in_sizes, int n_in,
                              void* d_out, int out_size, void* d_ws, size_t ws_size,
                              hipStream_t stream){
  const float* x1    = (const float*)d_in[0];
  const float* x2    = (const float*)d_in[1];
  const float* qkv_w = (const float*)d_in[2];
  const float* proj_w= (const float*)d_in[3];
  const float* proj_b= (const float*)d_in[4];
  const float* pw    = (const float*)d_in[5];
  const float* pb    = (const float*)d_in[6];
  const float* g1    = (const float*)d_in[7];
  const float* b1    = (const float*)d_in[8];
  const float* w1    = (const float*)d_in[9];
  const float* c1    = (const float*)d_in[10];
  const float* g2    = (const float*)d_in[11];
  const float* b2    = (const float*)d_in[12];
  const float* w2    = (const float*)d_in[13];
  const float* c2    = (const float*)d_in[14];
  const float* g3    = (const float*)d_in[15];
  const float* b3    = (const float*)d_in[16];
  const float* w3    = (const float*)d_in[17];
  const float* c3    = (const float*)d_in[18];
  const float* dw_w  = (const float*)d_in[19];
  const float* dw_b  = (const float*)d_in[20];
  const float* bn1_g = (const float*)d_in[21];
  const float* bn1_b = (const float*)d_in[22];
  const float* bn1_m = (const float*)d_in[23];
  const float* bn1_v = (const float*)d_in[24];
  const float* si_w1 = (const float*)d_in[25];
  const float* si_b1 = (const float*)d_in[26];
  const float* bn2_g = (const float*)d_in[27];
  const float* bn2_b = (const float*)d_in[28];
  const float* bn2_m = (const float*)d_in[29];
  const float* bn2_v = (const float*)d_in[30];
  const float* si_w2 = (const float*)d_in[31];
  const float* si_b2 = (const float*)d_in[32];
  float* out = (float*)d_out;

  char* ws = (char*)d_ws;
  const size_t SZ  = (size_t)BDIM * LL * CC;   // 25,165,824 elements
  const size_t SZB = SZ * 2;                   // bf16 bytes per buffer
  ushortT* q1   = (ushortT*)(ws);
  ushortT* v1   = (ushortT*)(ws + SZB);
  ushortT* k2   = (ushortT*)(ws + 2*SZB);
  ushortT* att  = (ushortT*)(ws + 3*SZB);
  float*   gate = (float*)  (ws + 4*SZB);
  float*   pos  = (float*)  (ws + 4*SZB + (size_t)BDIM*LL*sizeof(float));
  ushortT* wbf  = (ushortT*)(ws + 4*SZB + (size_t)BDIM*LL*sizeof(float) + 16384);
  ushortT* wproj = wbf + WQKV_ELEMS;
  ushortT* wsi   = wproj + WPROJ_ELEMS;
  float*   gparam = (float*)(wbf + WQKV_ELEMS + WPROJ_ELEMS + WSI_ELEMS);
  float*   cparam = gparam + 3*CBh;
  ushortT* dwt    = (ushortT*)(cparam + 2*CC);
  ushortT* convx = q1;   // q1 dead after attention

  k_pos<<<dim3(2), dim3(256), 0, stream>>>(pw,pb,g1,b1,w1,c1,g2,b2,w2,c2,g3,b3,w3,c3,pos);
  k_cvtw<<<dim3((WALL_PAIRS+255)/256), dim3(256), 0, stream>>>(qkv_w, proj_w, si_w1,
      si_b1, bn2_g, bn2_b, bn2_m, bn2_v, si_w2,
      dw_w, dw_b, bn1_g, bn1_b, bn1_m, bn1_v, wbf, gparam, cparam, dwt);
  k_qkv<<<dim3(256,3), dim3(512), 0, stream>>>(x1, x2, wbf, q1, k2, v1);
  k_attn<4,16><<<dim3(2048), dim3(256), 0, stream>>>(q1, k2, v1, pos, att);
  k_attn<16,4><<<dim3(2048), dim3(256), 0, stream>>>(q1, k2, v1, pos, att);
  k_conv<<<dim3((unsigned)(SZ/8/256)), dim3(256), 0, stream>>>(v1, dwt, cparam, convx);
  k_gate<<<dim3(1024), dim3(256), 0, stream>>>(att, wsi, gparam, si_b2, gate);
  k_proj<<<dim3(256), dim3(512), 0, stream>>>(att, convx, gate, wproj, proj_b, out);
}

// Round 11
// 475.324 us; speedup vs baseline: 1.8207x; 1.8207x over previous
//
#include <hip/hip_runtime.h>
#include <hip/hip_bf16.h>
#include <math.h>

#define BDIM 8
#define HH 128
#define WW 128
#define LL (HH*WW)          // 16384
#define CC 192
#define CBh 96
#define HBn 4
#define HDd 24
#define PD 6
#define RTAB 217            // (2*4-1)*(2*16-1) for both branches

typedef unsigned short ushortT;
typedef __bf16 bf16x8 __attribute__((ext_vector_type(8)));
typedef float f32x4 __attribute__((ext_vector_type(4)));

__device__ __forceinline__ float b2f(ushortT u){
  union { float f; unsigned u; } x; x.u = ((unsigned)u) << 16; return x.f;
}
__device__ __forceinline__ ushortT f2b(float f){
  union { float f; unsigned u; } x; x.f = f;
  unsigned r = x.u + 0x7fffu + ((x.u >> 16) & 1u);
  return (ushortT)(r >> 16);
}
__device__ __forceinline__ float lo16(unsigned u){ union { float f; unsigned u; } x; x.u = u << 16; return x.f; }
__device__ __forceinline__ float hi16(unsigned u){ union { float f; unsigned u; } x; x.u = u & 0xffff0000u; return x.f; }
__device__ __forceinline__ unsigned pack2(float a, float b){
  return (unsigned)f2b(a) | ((unsigned)f2b(b) << 16);
}
__device__ __forceinline__ void unpack8(uint4 u, float* f){
  f[0]=lo16(u.x); f[1]=hi16(u.x); f[2]=lo16(u.y); f[3]=hi16(u.y);
  f[4]=lo16(u.z); f[5]=hi16(u.z); f[6]=lo16(u.w); f[7]=hi16(u.w);
}
// v_cvt_pk_bf16_f32 via HIP intrinsic (RNE)
__device__ __forceinline__ unsigned cvt2(float a, float b){
  __hip_bfloat162 h = __float22bfloat162_rn(float2{a, b});
  union { __hip_bfloat162 h; unsigned u; } c; c.h = h; return c.u;
}
__device__ __forceinline__ float gelu_exact(float x){
  return 0.5f * x * (1.0f + erff(x * 0.70710678118654752f));
}

union ABu { unsigned u[4]; bf16x8 v; };

// ---- LDS weight staging: full 192x192 bf16 slice (73728 B), XOR-swizzled ----
// byte ^= ((row&7)<<4): consecutive lanes hit consecutive 16B slots (measured
// 0 conflicts in r6/r8; the 64B-stride variant measured 3.5M — keep THIS layout).
__device__ __forceinline__ void stage_B512(const ushortT* __restrict__ Wsrc, char* lds){
  int t = threadIdx.x;
  #pragma unroll
  for (int i = 0; i < 9; i++){
    int c = t + i*512;                 // 16B-chunk index, 4608 total
    int n = c / 24, kc = c - n*24;     // row, chunk-in-row
    uint4 v = *(const uint4*)(const void*)(Wsrc + n*CC + kc*8);
    int byte = n*384 + kc*16;
    byte ^= ((n & 7) << 4);
    *(uint4*)(lds + byte) = v;
  }
}
__device__ __forceinline__ bf16x8 ldsB(const char* lds, int row, int kbyte){
  int byte = row*384 + kbyte;
  byte ^= ((row & 7) << 4);
  return *(const bf16x8*)(lds + byte);
}

// ---------------- K0: dynamic position-bias MLP -> pos[2][217][4] ----------------
__device__ __forceinline__ void ln_relu6(float* p, const float* g, const float* b){
  float m = 0.f;
  #pragma unroll
  for (int j=0;j<PD;j++) m += p[j];
  m *= (1.0f/PD);
  float v = 0.f;
  #pragma unroll
  for (int j=0;j<PD;j++){ float d = p[j]-m; v += d*d; }
  v *= (1.0f/PD);
  float is = rsqrtf(v + 1e-5f);
  #pragma unroll
  for (int j=0;j<PD;j++){ float t = (p[j]-m)*is*g[j] + b[j]; p[j] = t > 0.f ? t : 0.f; }
}
__device__ __forceinline__ void mm6(float* p, const float* w, const float* c){
  float q[PD];
  #pragma unroll
  for (int j=0;j<PD;j++){
    float a = c[j];
    #pragma unroll
    for (int i=0;i<PD;i++) a += p[i]*w[j*PD+i];
    q[j] = a;
  }
  #pragma unroll
  for (int j=0;j<PD;j++) p[j] = q[j];
}

__global__ void k_pos(const float* __restrict__ pw, const float* __restrict__ pb,
                      const float* __restrict__ g1, const float* __restrict__ b1,
                      const float* __restrict__ w1, const float* __restrict__ c1,
                      const float* __restrict__ g2, const float* __restrict__ b2,
                      const float* __restrict__ w2, const float* __restrict__ c2,
                      const float* __restrict__ g3, const float* __restrict__ b3,
                      const float* __restrict__ w3, const float* __restrict__ c3,
                      float* __restrict__ pos){
  int br = blockIdx.x;
  int r = threadIdx.x;
  if (r >= RTAB) return;
  int Hsp = br ? 16 : 4, Wsp = br ? 4 : 16;
  int W2 = 2*Wsp - 1;
  float bi0 = (float)(r / W2 - (Hsp-1));
  float bi1 = (float)(r % W2 - (Wsp-1));
  const float* PW = pw + br*PD*2;
  const float* PB = pb + br*PD;
  float p[PD];
  #pragma unroll
  for (int j=0;j<PD;j++) p[j] = PW[j*2]*bi0 + PW[j*2+1]*bi1 + PB[j];
  ln_relu6(p, g1+br*PD, b1+br*PD);
  mm6(p, w1+br*PD*PD, c1+br*PD);
  ln_relu6(p, g2+br*PD, b2+br*PD);
  mm6(p, w2+br*PD*PD, c2+br*PD);
  ln_relu6(p, g3+br*PD, b3+br*PD);
  const float* W3 = w3 + br*HBn*PD;
  const float* C3 = c3 + br*HBn;
  #pragma unroll
  for (int h=0;h<HBn;h++){
    float a = C3[h];
    #pragma unroll
    for (int i=0;i<PD;i++) a += p[i]*W3[h*PD+i];
    pos[((size_t)br*RTAB + r)*HBn + h] = a;
  }
}

// ---------------- K-cvt: convert weights to bf16; fold BN params; build conv tables ----------------
#define WQKV_ELEMS (3*CC*CC)                     // 110592
#define WPROJ_ELEMS (CC*CC)                      // 36864
#define WSI_ELEMS (CC*CBh)                       // 18432
#define WALL_PAIRS ((WQKV_ELEMS+WPROJ_ELEMS+WSI_ELEMS)/2)  // 82944

__global__ void k_cvtw(const float* __restrict__ qkv_w, const float* __restrict__ proj_w,
                       const float* __restrict__ si_w1,
                       const float* __restrict__ si_b1,
                       const float* __restrict__ g, const float* __restrict__ bb,
                       const float* __restrict__ mn, const float* __restrict__ vv,
                       const float* __restrict__ si_w2,
                       const float* __restrict__ dw_w, const float* __restrict__ dw_b,
                       const float* __restrict__ bn1_g, const float* __restrict__ bn1_b,
                       const float* __restrict__ bn1_m, const float* __restrict__ bn1_v,
                       ushortT* __restrict__ wb, float* __restrict__ gparam,
                       float* __restrict__ cparam, ushortT* __restrict__ dwt){
  int t = threadIdx.x;
  if (blockIdx.x == 0 && t < CBh){
    float sc = g[t]*rsqrtf(vv[t]+1e-5f);
    gparam[t]        = sc;                                   // scale
    gparam[CBh+t]    = (si_b1[t]-mn[t])*sc + bb[t];          // folded bias
    gparam[2*CBh+t]  = si_w2[t];                             // w2
  }
  if (blockIdx.x == 1){
    if (t < CC){
      float sc = bn1_g[t]*rsqrtf(bn1_v[t]+1e-5f);
      cparam[t]      = sc;
      cparam[CC+t]   = (dw_b[t]-bn1_m[t])*sc + bn1_b[t];
    }
    for (int i = t; i < 9*CC; i += 256){
      int k = i / CC, c = i - k*CC;
      dwt[i] = f2b(dw_w[c*9 + k]);
    }
  }
  int i = blockIdx.x*256 + t;
  if (i >= WALL_PAIRS) return;
  int e = i*2;
  float a, b;
  if (e < WQKV_ELEMS){ a = qkv_w[e]; b = qkv_w[e+1]; }
  else if (e < WQKV_ELEMS+WPROJ_ELEMS){ a = proj_w[e-WQKV_ELEMS]; b = proj_w[e-WQKV_ELEMS+1]; }
  else { a = si_w1[e-WQKV_ELEMS-WPROJ_ELEMS]; b = si_w1[e-WQKV_ELEMS-WPROJ_ELEMS+1]; }
  *(unsigned*)(void*)(wb + e) = cvt2(a, b);
}

// ---------------- K1: QKV GEMM via MFMA, whole B in LDS, q+v merged ----------------
// Grid (1024,2); block 512 thr = 8 waves of 16 rows (128 rows/block).
// z=0: x1 -> q1 (Wq) then re-stage Wv, reuse saved bf16 A-frags -> v1 (x1 read ONCE).
// z=1: x2 -> k2 (Wk), single pass.
__global__ __launch_bounds__(512, 4) void k_qkv(const float* __restrict__ x1, const float* __restrict__ x2,
                                                const ushortT* __restrict__ wb,
                                                ushortT* __restrict__ q1, ushortT* __restrict__ k2,
                                                ushortT* __restrict__ v1){
  __shared__ char Bs[CC*CC*2];     // 73728 B
  int z = blockIdx.y;
  const float* src = z ? x2 : x1;
  stage_B512(wb + (size_t)(z ? 1 : 0)*CC*CC, Bs);   // Wq or Wk

  int w = threadIdx.x >> 6, l = threadIdx.x & 63;
  int row0 = blockIdx.x*128 + w*16;
  int lr = l & 15;            // frag row (A) / col (B)
  int hk = l >> 4;            // k-phase
  int crow = hk*4, ccol = lr;

  ABu asave[6];               // 24 VGPRs of bf16 A-frags, reused in pass 2
  f32x4 acc[12];
  #pragma unroll
  for (int n=0; n<12; n++) acc[n] = (f32x4){0.f,0.f,0.f,0.f};

  const float* ap = src + (size_t)(row0 + lr)*CC + hk*8;
  __syncthreads();

  #pragma unroll
  for (int ks = 0; ks < 6; ks++){
    float4 p0 = *(const float4*)(ap + ks*32);
    float4 p1 = *(const float4*)(ap + ks*32 + 4);
    asave[ks].u[0] = cvt2(p0.x, p0.y); asave[ks].u[1] = cvt2(p0.z, p0.w);
    asave[ks].u[2] = cvt2(p1.x, p1.y); asave[ks].u[3] = cvt2(p1.z, p1.w);
    int kb = ks*64 + hk*16;
    #pragma unroll
    for (int n=0; n<12; n++){
      bf16x8 bfr = ldsB(Bs, n*16 + lr, kb);
      acc[n] = __builtin_amdgcn_mfma_f32_16x16x32_bf16(asave[ks].v, bfr, acc[n], 0, 0, 0);
    }
  }
  ushortT* dst1 = z ? k2 : q1;
  #pragma unroll
  for (int n=0; n<12; n++)
    #pragma unroll
    for (int r=0; r<4; r++){
      int m = row0 + crow + r;
      dst1[(size_t)m*CC + n*16 + ccol] = f2b(acc[n][r]);
    }

  if (z == 0){
    __syncthreads();                       // all waves done reading Wq
    stage_B512(wb + (size_t)2*CC*CC, Bs);  // Wv
    #pragma unroll
    for (int n=0; n<12; n++) acc[n] = (f32x4){0.f,0.f,0.f,0.f};
    __syncthreads();
    #pragma unroll
    for (int ks = 0; ks < 6; ks++){
      int kb = ks*64 + hk*16;
      #pragma unroll
      for (int n=0; n<12; n++){
        bf16x8 bfr = ldsB(Bs, n*16 + lr, kb);
        acc[n] = __builtin_amdgcn_mfma_f32_16x16x32_bf16(asave[ks].v, bfr, acc[n], 0, 0, 0);
      }
    }
    #pragma unroll
    for (int n=0; n<12; n++)
      #pragma unroll
      for (int r=0; r<4; r++){
        int m = row0 + crow + r;
        v1[(size_t)m*CC + n*16 + ccol] = f2b(acc[n][r]);
      }
  }
}

// ---------------- K2: windowed attention (one branch per template) ----------------
template<int HSP, int WSP>
__global__ __launch_bounds__(256) void k_attn(const ushortT* __restrict__ q1, const ushortT* __restrict__ k2,
                                              const ushortT* __restrict__ v1, const float* __restrict__ pos,
                                              ushortT* __restrict__ att){
  constexpr int BR = (HSP == 4) ? 0 : 1;
  constexpr int NWH = HH / HSP, NWW = WW / WSP;
  constexpr int CH0 = BR * CBh;
  __shared__ float ks[64][CBh];
  __shared__ float vs[64][CBh];
  __shared__ float ps[RTAB*HBn];
  int t = threadIdx.x;
  int wid = blockIdx.x;
  int b = wid / (NWH*NWW);
  int rem = wid - b*(NWH*NWW);
  int hi = rem / NWW, wj = rem - hi*NWW;
  for (int i = t; i < RTAB*HBn; i += 256) ps[i] = pos[(size_t)BR*RTAB*HBn + i];
  #pragma unroll
  for (int r = 0; r < 3; r++){
    int idx = t + r*256;        // < 768 = 64 pix * 12 segs
    int pix = idx / 12, seg = idx - pix*12;
    int ii = pix / WSP, jj = pix - ii*WSP;
    size_t base = (((size_t)b*LL) + (size_t)(hi*HSP+ii)*WW + wj*WSP + jj)*CC + CH0 + seg*8;
    uint4 uk = *(const uint4*)(const void*)(k2 + base);
    unpack8(uk, &ks[pix][seg*8]);
    uint4 uv = *(const uint4*)(const void*)(v1 + base);
    unpack8(uv, &vs[pix][seg*8]);
  }
  __syncthreads();
  int h = t >> 6, lane = t & 63;
  int i1 = lane / WSP, j1 = lane - i1*WSP;
  size_t lq = ((size_t)b*LL) + (size_t)(hi*HSP+i1)*WW + wj*WSP + j1;
  const ushortT* qrow = q1 + lq*CC + CH0 + h*HDd;
  float qf[HDd];
  #pragma unroll
  for (int d0 = 0; d0 < HDd; d0 += 8){
    uint4 u = *(const uint4*)(const void*)(qrow + d0);
    unpack8(u, &qf[d0]);
  }
  #pragma unroll
  for (int d=0; d<HDd; d++) qf[d] *= 0.20412414523193154f;   // 1/sqrt(24)
  float lg[64];
  #pragma unroll
  for (int m = 0; m < 64; m++){
    const float* kr = &ks[m][h*HDd];
    float s = 0.f;
    #pragma unroll
    for (int d=0; d<HDd; d++) s = fmaf(qf[d], kr[d], s);
    int i2 = m / WSP, j2 = m - i2*WSP;
    int ridx = (i1-i2+HSP-1)*(2*WSP-1) + (j1-j2+WSP-1);
    lg[m] = s + ps[ridx*HBn + h];
  }
  float mx = lg[0];
  #pragma unroll
  for (int m=1;m<64;m++) mx = fmaxf(mx, lg[m]);
  float sum = 0.f;
  #pragma unroll
  for (int m=0;m<64;m++){ lg[m] = __expf(lg[m]-mx); sum += lg[m]; }
  float inv = 1.0f / sum;
  float z[HDd];
  #pragma unroll
  for (int d=0;d<HDd;d++) z[d] = 0.f;
  #pragma unroll
  for (int m=0;m<64;m++){
    float p = lg[m]*inv;
    const float* vr = &vs[m][h*HDd];
    #pragma unroll
    for (int d=0;d<HDd;d++) z[d] = fmaf(p, vr[d], z[d]);
  }
  ushortT* orow = att + lq*CC + CH0 + h*HDd;
  #pragma unroll
  for (int d0=0; d0<HDd; d0+=8){
    uint4 u;
    u.x = pack2(z[d0+0], z[d0+1]);
    u.y = pack2(z[d0+2], z[d0+3]);
    u.z = pack2(z[d0+4], z[d0+5]);
    u.w = pack2(z[d0+6], z[d0+7]);
    *(uint4*)(void*)(orow + d0) = u;
  }
}

// ---------------- K3: depthwise 3x3 conv + BN + GELU, 8 channels/thread ----------------
__global__ __launch_bounds__(256) void k_conv(const ushortT* __restrict__ v1,
                                              const ushortT* __restrict__ dwt,
                                              const float* __restrict__ cparam,
                                              ushortT* __restrict__ cx){
  int tid = blockIdx.x*256 + threadIdx.x;     // SZ/8 total
  int grp = tid % 24;
  int pix = tid / 24;
  int j = pix & (WW-1);
  int rest = pix >> 7;
  int i = rest & (HH-1);
  int b = rest >> 7;
  int c0 = grp*8;
  uint4 wreg[9];
  #pragma unroll
  for (int k=0;k<9;k++) wreg[k] = *(const uint4*)(const void*)(dwt + k*CC + c0);
  float acc[8];
  #pragma unroll
  for (int t2=0;t2<8;t2++) acc[t2]=0.f;
  #pragma unroll
  for (int ki=0;ki<3;ki++){
    int ii = i + ki - 1;
    if (ii < 0 || ii >= HH) continue;
    #pragma unroll
    for (int kj=0;kj<3;kj++){
      int jj = j + kj - 1;
      if (jj < 0 || jj >= WW) continue;
      uint4 uv = *(const uint4*)(const void*)(v1 + (((size_t)b*LL) + (size_t)ii*WW + jj)*CC + c0);
      float fv[8], fw[8];
      unpack8(uv, fv);
      unpack8(wreg[ki*3+kj], fw);
      #pragma unroll
      for (int t2=0;t2<8;t2++) acc[t2] = fmaf(fv[t2], fw[t2], acc[t2]);
    }
  }
  float4 s0 = *(const float4*)(cparam + c0);
  float4 s1 = *(const float4*)(cparam + c0 + 4);
  float4 o0 = *(const float4*)(cparam + CC + c0);
  float4 o1 = *(const float4*)(cparam + CC + c0 + 4);
  float scv[8] = {s0.x,s0.y,s0.z,s0.w,s1.x,s1.y,s1.z,s1.w};
  float ofv[8] = {o0.x,o0.y,o0.z,o0.w,o1.x,o1.y,o1.z,o1.w};
  unsigned ou[4];
  #pragma unroll
  for (int t2=0;t2<4;t2++){
    float y0 = gelu_exact(acc[2*t2]  *scv[2*t2]   + ofv[2*t2]);
    float y1 = gelu_exact(acc[2*t2+1]*scv[2*t2+1] + ofv[2*t2+1]);
    ou[t2] = pack2(y0, y1);
  }
  uint4 res; res.x=ou[0]; res.y=ou[1]; res.z=ou[2]; res.w=ou[3];
  *(uint4*)(void*)(cx + (size_t)pix*CC + c0) = res;
}

// ---------------- K4: per-pixel SE gate via MFMA ----------------
__global__ __launch_bounds__(256) void k_gate(const ushortT* __restrict__ att,
                                              const ushortT* __restrict__ wsi,
                                              const float* __restrict__ gparam,
                                              const float* __restrict__ si_b2,
                                              float* __restrict__ gate){
  int w = threadIdx.x >> 6, l = threadIdx.x & 63;
  int row0 = blockIdx.x*128 + w*32;
  int lr = l & 15;
  int lk = (l >> 4) * 8;
  f32x4 acc[2][6];
  #pragma unroll
  for (int rt=0; rt<2; rt++)
    #pragma unroll
    for (int n=0; n<6; n++) acc[rt][n] = (f32x4){0.f,0.f,0.f,0.f};
  #pragma unroll
  for (int ks = 0; ks < 6; ks++){
    int k0 = ks*32 + lk;
    bf16x8 a0 = *(const bf16x8*)(const void*)(att + (size_t)(row0 + lr)*CC + k0);
    bf16x8 a1 = *(const bf16x8*)(const void*)(att + (size_t)(row0 + 16 + lr)*CC + k0);
    #pragma unroll
    for (int n=0; n<6; n++){
      bf16x8 bfr = *(const bf16x8*)(const void*)(wsi + (size_t)(n*16 + lr)*CC + k0);
      acc[0][n] = __builtin_amdgcn_mfma_f32_16x16x32_bf16(a0, bfr, acc[0][n], 0, 0, 0);
      acc[1][n] = __builtin_amdgcn_mfma_f32_16x16x32_bf16(a1, bfr, acc[1][n], 0, 0, 0);
    }
  }
  int crow = (l >> 4) * 4, ccol = l & 15;
  float sc6[6], cb6[6], w26[6];
  #pragma unroll
  for (int n=0; n<6; n++){
    int o = n*16 + ccol;
    sc6[n] = gparam[o];
    cb6[n] = gparam[CBh + o];
    w26[n] = gparam[2*CBh + o];
  }
  float sb2 = si_b2[0];
  float ps[2][4];
  #pragma unroll
  for (int rt=0; rt<2; rt++)
    #pragma unroll
    for (int r=0; r<4; r++) ps[rt][r] = 0.f;
  #pragma unroll
  for (int rt=0; rt<2; rt++)
    #pragma unroll
    for (int n=0; n<6; n++)
      #pragma unroll
      for (int r=0; r<4; r++){
        float x = acc[rt][n][r]*sc6[n] + cb6[n];
        ps[rt][r] += gelu_exact(x) * w26[n];
      }
  #pragma unroll
  for (int rt=0; rt<2; rt++)
    #pragma unroll
    for (int r=0; r<4; r++){
      float v = ps[rt][r];
      #pragma unroll
      for (int off = 1; off < 16; off <<= 1) v += __shfl_xor(v, off, 64);
      ps[rt][r] = v;
    }
  if (ccol == 0){
    #pragma unroll
    for (int rt=0; rt<2; rt++)
      #pragma unroll
      for (int r=0; r<4; r++){
        int m = row0 + rt*16 + crow + r;
        gate[m] = 1.0f / (1.0f + __expf(-(ps[rt][r] + sb2)));
      }
  }
}

// ---------------- K5: proj GEMM via MFMA, whole B in LDS, 16-row waves, fused gate ----------------
__global__ __launch_bounds__(512, 4) void k_proj(const ushortT* __restrict__ att, const ushortT* __restrict__ cx,
                                                 const float* __restrict__ gate,
                                                 const ushortT* __restrict__ wp, const float* __restrict__ pbias,
                                                 float* __restrict__ out){
  __shared__ char Bs[CC*CC*2];     // 73728 B
  stage_B512(wp, Bs);

  int w = threadIdx.x >> 6, l = threadIdx.x & 63;
  int row0 = blockIdx.x*128 + w*16;
  int lr = l & 15;
  int hk = l >> 4;
  float gv = gate[row0 + lr];
  f32x4 acc[12];
  #pragma unroll
  for (int n=0; n<12; n++) acc[n] = (f32x4){0.f,0.f,0.f,0.f};

  size_t base = (size_t)(row0 + lr)*CC + hk*8;
  __syncthreads();

  #pragma unroll
  for (int ks = 0; ks < 6; ks++){
    uint4 ua = *(const uint4*)(const void*)(att + base + ks*32);
    uint4 uc = *(const uint4*)(const void*)(cx  + base + ks*32);
    float fa[8], fc[8];
    unpack8(ua, fa); unpack8(uc, fc);
    #pragma unroll
    for (int j=0;j<8;j++) fa[j] = fmaf(gv, fc[j], fa[j]);
    ABu a;
    a.u[0] = cvt2(fa[0], fa[1]); a.u[1] = cvt2(fa[2], fa[3]);
    a.u[2] = cvt2(fa[4], fa[5]); a.u[3] = cvt2(fa[6], fa[7]);
    int kb = ks*64 + hk*16;
    #pragma unroll
    for (int n=0; n<12; n++){
      bf16x8 bfr = ldsB(Bs, n*16 + lr, kb);
      acc[n] = __builtin_amdgcn_mfma_f32_16x16x32_bf16(a.v, bfr, acc[n], 0, 0, 0);
    }
  }
  int crow = hk*4, ccol = lr;
  #pragma unroll
  for (int n=0; n<12; n++){
    float bv = pbias[n*16 + ccol];
    #pragma unroll
    for (int r=0; r<4; r++){
      int m = row0 + crow + r;
      out[(size_t)m*CC + n*16 + ccol] = acc[n][r] + bv;
    }
  }
}

extern "C" void kernel_launch(void* const* d_in, const int* in_sizes, int n_in,
                              void* d_out, int out_size, void* d_ws, size_t ws_size,
                              hipStream_t stream){
  const float* x1    = (const float*)d_in[0];
  const float* x2    = (const float*)d_in[1];
  const float* qkv_w = (const float*)d_in[2];
  const float* proj_w= (const float*)d_in[3];
  const float* proj_b= (const float*)d_in[4];
  const float* pw    = (const float*)d_in[5];
  const float* pb    = (const float*)d_in[6];
  const float* g1    = (const float*)d_in[7];
  const float* b1    = (const float*)d_in[8];
  const float* w1    = (const float*)d_in[9];
  const float* c1    = (const float*)d_in[10];
  const float* g2    = (const float*)d_in[11];
  const float* b2    = (const float*)d_in[12];
  const float* w2    = (const float*)d_in[13];
  const float* c2    = (const float*)d_in[14];
  const float* g3    = (const float*)d_in[15];
  const float* b3    = (const float*)d_in[16];
  const float* w3    = (const float*)d_in[17];
  const float* c3    = (const float*)d_in[18];
  const float* dw_w  = (const float*)d_in[19];
  const float* dw_b  = (const float*)d_in[20];
  const float* bn1_g = (const float*)d_in[21];
  const float* bn1_b = (const float*)d_in[22];
  const float* bn1_m = (const float*)d_in[23];
  const float* bn1_v = (const float*)d_in[24];
  const float* si_w1 = (const float*)d_in[25];
  const float* si_b1 = (const float*)d_in[26];
  const float* bn2_g = (const float*)d_in[27];
  const float* bn2_b = (const float*)d_in[28];
  const float* bn2_m = (const float*)d_in[29];
  const float* bn2_v = (const float*)d_in[30];
  const float* si_w2 = (const float*)d_in[31];
  const float* si_b2 = (const float*)d_in[32];
  float* out = (float*)d_out;

  char* ws = (char*)d_ws;
  const size_t SZ  = (size_t)BDIM * LL * CC;   // 25,165,824 elements
  const size_t SZB = SZ * 2;                   // bf16 bytes per buffer
  ushortT* q1   = (ushortT*)(ws);
  ushortT* v1   = (ushortT*)(ws + SZB);
  ushortT* k2   = (ushortT*)(ws + 2*SZB);
  ushortT* att  = (ushortT*)(ws + 3*SZB);
  float*   gate = (float*)  (ws + 4*SZB);
  float*   pos  = (float*)  (ws + 4*SZB + (size_t)BDIM*LL*sizeof(float));
  ushortT* wbf  = (ushortT*)(ws + 4*SZB + (size_t)BDIM*LL*sizeof(float) + 16384);
  ushortT* wproj = wbf + WQKV_ELEMS;
  ushortT* wsi   = wproj + WPROJ_ELEMS;
  float*   gparam = (float*)(wbf + WQKV_ELEMS + WPROJ_ELEMS + WSI_ELEMS);
  float*   cparam = gparam + 3*CBh;
  ushortT* dwt    = (ushortT*)(cparam + 2*CC);
  ushortT* convx = q1;   // q1 dead after attention

  k_pos<<<dim3(2), dim3(256), 0, stream>>>(pw,pb,g1,b1,w1,c1,g2,b2,w2,c2,g3,b3,w3,c3,pos);
  k_cvtw<<<dim3((WALL_PAIRS+255)/256), dim3(256), 0, stream>>>(qkv_w, proj_w, si_w1,
      si_b1, bn2_g, bn2_b, bn2_m, bn2_v, si_w2,
      dw_w, dw_b, bn1_g, bn1_b, bn1_m, bn1_v, wbf, gparam, cparam, dwt);
  k_qkv<<<dim3(1024,2), dim3(512), 0, stream>>>(x1, x2, wbf, q1, k2, v1);
  k_attn<4,16><<<dim3(2048), dim3(256), 0, stream>>>(q1, k2, v1, pos, att);
  k_attn<16,4><<<dim3(2048), dim3(256), 0, stream>>>(q1, k2, v1, pos, att);
  k_conv<<<dim3((unsigned)(SZ/8/256)), dim3(256), 0, stream>>>(v1, dwt, cparam, convx);
  k_gate<<<dim3(1024), dim3(256), 0, stream>>>(att, wsi, gparam, si_b2, gate);
  k_proj<<<dim3(1024), dim3(512), 0, stream>>>(att, convx, gate, wproj, proj_b, out);
}

// Round 12
// 411.335 us; speedup vs baseline: 2.1039x; 1.1556x over previous
//
#include <hip/hip_runtime.h>
#include <hip/hip_bf16.h>
#include <math.h>

#define BDIM 8
#define HH 128
#define WW 128
#define LL (HH*WW)          // 16384
#define CC 192
#define CBh 96
#define HBn 4
#define HDd 24
#define PD 6
#define RTAB 217            // (2*4-1)*(2*16-1) for both branches

typedef unsigned short ushortT;
typedef __bf16 bf16x8 __attribute__((ext_vector_type(8)));
typedef float f32x4 __attribute__((ext_vector_type(4)));

__device__ __forceinline__ float b2f(ushortT u){
  union { float f; unsigned u; } x; x.u = ((unsigned)u) << 16; return x.f;
}
__device__ __forceinline__ ushortT f2b(float f){
  union { float f; unsigned u; } x; x.f = f;
  unsigned r = x.u + 0x7fffu + ((x.u >> 16) & 1u);
  return (ushortT)(r >> 16);
}
__device__ __forceinline__ float lo16(unsigned u){ union { float f; unsigned u; } x; x.u = u << 16; return x.f; }
__device__ __forceinline__ float hi16(unsigned u){ union { float f; unsigned u; } x; x.u = u & 0xffff0000u; return x.f; }
__device__ __forceinline__ unsigned pack2(float a, float b){
  return (unsigned)f2b(a) | ((unsigned)f2b(b) << 16);
}
__device__ __forceinline__ void unpack8(uint4 u, float* f){
  f[0]=lo16(u.x); f[1]=hi16(u.x); f[2]=lo16(u.y); f[3]=hi16(u.y);
  f[4]=lo16(u.z); f[5]=hi16(u.z); f[6]=lo16(u.w); f[7]=hi16(u.w);
}
// v_cvt_pk_bf16_f32 via HIP intrinsic (RNE)
__device__ __forceinline__ unsigned cvt2(float a, float b){
  __hip_bfloat162 h = __float22bfloat162_rn(float2{a, b});
  union { __hip_bfloat162 h; unsigned u; } c; c.h = h; return c.u;
}
__device__ __forceinline__ float gelu_exact(float x){
  return 0.5f * x * (1.0f + erff(x * 0.70710678118654752f));
}

union ABu { unsigned u[4]; bf16x8 v; };

// ---- LDS weight staging: full 192x192 bf16 slice (73728 B), XOR-swizzled ----
// byte ^= ((row&7)<<4): consecutive lanes hit consecutive 16B slots (measured
// 0 conflicts in r6/r8; the 64B-stride variant measured 3.5M — keep THIS layout).
__device__ __forceinline__ void stage_B512(const ushortT* __restrict__ Wsrc, char* lds){
  int t = threadIdx.x;
  #pragma unroll
  for (int i = 0; i < 9; i++){
    int c = t + i*512;                 // 16B-chunk index, 4608 total
    int n = c / 24, kc = c - n*24;     // row, chunk-in-row
    uint4 v = *(const uint4*)(const void*)(Wsrc + n*CC + kc*8);
    int byte = n*384 + kc*16;
    byte ^= ((n & 7) << 4);
    *(uint4*)(lds + byte) = v;
  }
}
__device__ __forceinline__ bf16x8 ldsB(const char* lds, int row, int kbyte){
  int byte = row*384 + kbyte;
  byte ^= ((row & 7) << 4);
  return *(const bf16x8*)(lds + byte);
}

// ---------------- K0: dynamic position-bias MLP -> pos[2][217][4] ----------------
__device__ __forceinline__ void ln_relu6(float* p, const float* g, const float* b){
  float m = 0.f;
  #pragma unroll
  for (int j=0;j<PD;j++) m += p[j];
  m *= (1.0f/PD);
  float v = 0.f;
  #pragma unroll
  for (int j=0;j<PD;j++){ float d = p[j]-m; v += d*d; }
  v *= (1.0f/PD);
  float is = rsqrtf(v + 1e-5f);
  #pragma unroll
  for (int j=0;j<PD;j++){ float t = (p[j]-m)*is*g[j] + b[j]; p[j] = t > 0.f ? t : 0.f; }
}
__device__ __forceinline__ void mm6(float* p, const float* w, const float* c){
  float q[PD];
  #pragma unroll
  for (int j=0;j<PD;j++){
    float a = c[j];
    #pragma unroll
    for (int i=0;i<PD;i++) a += p[i]*w[j*PD+i];
    q[j] = a;
  }
  #pragma unroll
  for (int j=0;j<PD;j++) p[j] = q[j];
}

__global__ void k_pos(const float* __restrict__ pw, const float* __restrict__ pb,
                      const float* __restrict__ g1, const float* __restrict__ b1,
                      const float* __restrict__ w1, const float* __restrict__ c1,
                      const float* __restrict__ g2, const float* __restrict__ b2,
                      const float* __restrict__ w2, const float* __restrict__ c2,
                      const float* __restrict__ g3, const float* __restrict__ b3,
                      const float* __restrict__ w3, const float* __restrict__ c3,
                      float* __restrict__ pos){
  int br = blockIdx.x;
  int r = threadIdx.x;
  if (r >= RTAB) return;
  int Hsp = br ? 16 : 4, Wsp = br ? 4 : 16;
  int W2 = 2*Wsp - 1;
  float bi0 = (float)(r / W2 - (Hsp-1));
  float bi1 = (float)(r % W2 - (Wsp-1));
  const float* PW = pw + br*PD*2;
  const float* PB = pb + br*PD;
  float p[PD];
  #pragma unroll
  for (int j=0;j<PD;j++) p[j] = PW[j*2]*bi0 + PW[j*2+1]*bi1 + PB[j];
  ln_relu6(p, g1+br*PD, b1+br*PD);
  mm6(p, w1+br*PD*PD, c1+br*PD);
  ln_relu6(p, g2+br*PD, b2+br*PD);
  mm6(p, w2+br*PD*PD, c2+br*PD);
  ln_relu6(p, g3+br*PD, b3+br*PD);
  const float* W3 = w3 + br*HBn*PD;
  const float* C3 = c3 + br*HBn;
  #pragma unroll
  for (int h=0;h<HBn;h++){
    float a = C3[h];
    #pragma unroll
    for (int i=0;i<PD;i++) a += p[i]*W3[h*PD+i];
    pos[((size_t)br*RTAB + r)*HBn + h] = a;
  }
}

// ---------------- K-cvt: convert weights to bf16; fold BN params; build conv tables ----------------
#define WQKV_ELEMS (3*CC*CC)                     // 110592
#define WPROJ_ELEMS (CC*CC)                      // 36864
#define WSI_ELEMS (CC*CBh)                       // 18432
#define WALL_PAIRS ((WQKV_ELEMS+WPROJ_ELEMS+WSI_ELEMS)/2)  // 82944

__global__ void k_cvtw(const float* __restrict__ qkv_w, const float* __restrict__ proj_w,
                       const float* __restrict__ si_w1,
                       const float* __restrict__ si_b1,
                       const float* __restrict__ g, const float* __restrict__ bb,
                       const float* __restrict__ mn, const float* __restrict__ vv,
                       const float* __restrict__ si_w2,
                       const float* __restrict__ dw_w, const float* __restrict__ dw_b,
                       const float* __restrict__ bn1_g, const float* __restrict__ bn1_b,
                       const float* __restrict__ bn1_m, const float* __restrict__ bn1_v,
                       ushortT* __restrict__ wb, float* __restrict__ gparam,
                       float* __restrict__ cparam, ushortT* __restrict__ dwt){
  int t = threadIdx.x;
  if (blockIdx.x == 0 && t < CBh){
    float sc = g[t]*rsqrtf(vv[t]+1e-5f);
    gparam[t]        = sc;                                   // scale
    gparam[CBh+t]    = (si_b1[t]-mn[t])*sc + bb[t];          // folded bias
    gparam[2*CBh+t]  = si_w2[t];                             // w2
  }
  if (blockIdx.x == 1){
    if (t < CC){
      float sc = bn1_g[t]*rsqrtf(bn1_v[t]+1e-5f);
      cparam[t]      = sc;
      cparam[CC+t]   = (dw_b[t]-bn1_m[t])*sc + bn1_b[t];
    }
    for (int i = t; i < 9*CC; i += 256){
      int k = i / CC, c = i - k*CC;
      dwt[i] = f2b(dw_w[c*9 + k]);
    }
  }
  int i = blockIdx.x*256 + t;
  if (i >= WALL_PAIRS) return;
  int e = i*2;
  float a, b;
  if (e < WQKV_ELEMS){ a = qkv_w[e]; b = qkv_w[e+1]; }
  else if (e < WQKV_ELEMS+WPROJ_ELEMS){ a = proj_w[e-WQKV_ELEMS]; b = proj_w[e-WQKV_ELEMS+1]; }
  else { a = si_w1[e-WQKV_ELEMS-WPROJ_ELEMS]; b = si_w1[e-WQKV_ELEMS-WPROJ_ELEMS+1]; }
  *(unsigned*)(void*)(wb + e) = cvt2(a, b);
}

// ---------------- K1: QKV GEMM via MFMA, whole B in LDS, 16-row waves, 12-load A hoist ----------------
// Grid (1024,3); block 512 thr = 8 waves of 16 rows (128 rows/block).
// All 12 A float4 loads issued BEFORE the staging barrier; launch_bounds(512,2)
// gives the allocator headroom (~120 regs live) so the hoist stays in registers.
__global__ __launch_bounds__(512, 2) void k_qkv(const float* __restrict__ x1, const float* __restrict__ x2,
                                                const ushortT* __restrict__ wb,
                                                ushortT* __restrict__ q1, ushortT* __restrict__ k2,
                                                ushortT* __restrict__ v1){
  __shared__ char Bs[CC*CC*2];     // 73728 B
  int z = blockIdx.y;
  const float* src = (z == 1) ? x2 : x1;
  ushortT* dst = (z == 0) ? q1 : ((z == 1) ? k2 : v1);
  stage_B512(wb + (size_t)z*CC*CC, Bs);

  int w = threadIdx.x >> 6, l = threadIdx.x & 63;
  int row0 = blockIdx.x*128 + w*16;
  int lr = l & 15;            // frag row (A) / col (B)
  int hk = l >> 4;            // k-phase
  const float* ap = src + (size_t)(row0 + lr)*CC + hk*8;

  float4 buf[12];             // 48 VGPRs, 12 independent loads in flight
  #pragma unroll
  for (int ks = 0; ks < 6; ks++){
    buf[2*ks+0] = *(const float4*)(ap + ks*32);
    buf[2*ks+1] = *(const float4*)(ap + ks*32 + 4);
  }
  f32x4 acc[12];
  #pragma unroll
  for (int n=0; n<12; n++) acc[n] = (f32x4){0.f,0.f,0.f,0.f};
  __syncthreads();

  #pragma unroll
  for (int ks = 0; ks < 6; ks++){
    float4 p0 = buf[2*ks+0], p1 = buf[2*ks+1];
    ABu a;
    a.u[0] = cvt2(p0.x, p0.y); a.u[1] = cvt2(p0.z, p0.w);
    a.u[2] = cvt2(p1.x, p1.y); a.u[3] = cvt2(p1.z, p1.w);
    int kb = ks*64 + hk*16;
    #pragma unroll
    for (int n=0; n<12; n++){
      bf16x8 bfr = ldsB(Bs, n*16 + lr, kb);
      acc[n] = __builtin_amdgcn_mfma_f32_16x16x32_bf16(a.v, bfr, acc[n], 0, 0, 0);
    }
  }
  int crow = hk*4, ccol = lr;
  #pragma unroll
  for (int n=0; n<12; n++)
    #pragma unroll
    for (int r=0; r<4; r++){
      int m = row0 + crow + r;
      dst[(size_t)m*CC + n*16 + ccol] = f2b(acc[n][r]);
    }
}

// ---------------- K2: windowed attention (one branch per template) ----------------
template<int HSP, int WSP>
__global__ __launch_bounds__(256) void k_attn(const ushortT* __restrict__ q1, const ushortT* __restrict__ k2,
                                              const ushortT* __restrict__ v1, const float* __restrict__ pos,
                                              ushortT* __restrict__ att){
  constexpr int BR = (HSP == 4) ? 0 : 1;
  constexpr int NWH = HH / HSP, NWW = WW / WSP;
  constexpr int CH0 = BR * CBh;
  __shared__ float ks[64][CBh];
  __shared__ float vs[64][CBh];
  __shared__ float ps[RTAB*HBn];
  int t = threadIdx.x;
  int wid = blockIdx.x;
  int b = wid / (NWH*NWW);
  int rem = wid - b*(NWH*NWW);
  int hi = rem / NWW, wj = rem - hi*NWW;
  for (int i = t; i < RTAB*HBn; i += 256) ps[i] = pos[(size_t)BR*RTAB*HBn + i];
  #pragma unroll
  for (int r = 0; r < 3; r++){
    int idx = t + r*256;        // < 768 = 64 pix * 12 segs
    int pix = idx / 12, seg = idx - pix*12;
    int ii = pix / WSP, jj = pix - ii*WSP;
    size_t base = (((size_t)b*LL) + (size_t)(hi*HSP+ii)*WW + wj*WSP + jj)*CC + CH0 + seg*8;
    uint4 uk = *(const uint4*)(const void*)(k2 + base);
    unpack8(uk, &ks[pix][seg*8]);
    uint4 uv = *(const uint4*)(const void*)(v1 + base);
    unpack8(uv, &vs[pix][seg*8]);
  }
  __syncthreads();
  int h = t >> 6, lane = t & 63;
  int i1 = lane / WSP, j1 = lane - i1*WSP;
  size_t lq = ((size_t)b*LL) + (size_t)(hi*HSP+i1)*WW + wj*WSP + j1;
  const ushortT* qrow = q1 + lq*CC + CH0 + h*HDd;
  float qf[HDd];
  #pragma unroll
  for (int d0 = 0; d0 < HDd; d0 += 8){
    uint4 u = *(const uint4*)(const void*)(qrow + d0);
    unpack8(u, &qf[d0]);
  }
  #pragma unroll
  for (int d=0; d<HDd; d++) qf[d] *= 0.20412414523193154f;   // 1/sqrt(24)
  float lg[64];
  #pragma unroll
  for (int m = 0; m < 64; m++){
    const float* kr = &ks[m][h*HDd];
    float s = 0.f;
    #pragma unroll
    for (int d=0; d<HDd; d++) s = fmaf(qf[d], kr[d], s);
    int i2 = m / WSP, j2 = m - i2*WSP;
    int ridx = (i1-i2+HSP-1)*(2*WSP-1) + (j1-j2+WSP-1);
    lg[m] = s + ps[ridx*HBn + h];
  }
  float mx = lg[0];
  #pragma unroll
  for (int m=1;m<64;m++) mx = fmaxf(mx, lg[m]);
  float sum = 0.f;
  #pragma unroll
  for (int m=0;m<64;m++){ lg[m] = __expf(lg[m]-mx); sum += lg[m]; }
  float inv = 1.0f / sum;
  float z[HDd];
  #pragma unroll
  for (int d=0;d<HDd;d++) z[d] = 0.f;
  #pragma unroll
  for (int m=0;m<64;m++){
    float p = lg[m]*inv;
    const float* vr = &vs[m][h*HDd];
    #pragma unroll
    for (int d=0;d<HDd;d++) z[d] = fmaf(p, vr[d], z[d]);
  }
  ushortT* orow = att + lq*CC + CH0 + h*HDd;
  #pragma unroll
  for (int d0=0; d0<HDd; d0+=8){
    uint4 u;
    u.x = pack2(z[d0+0], z[d0+1]);
    u.y = pack2(z[d0+2], z[d0+3]);
    u.z = pack2(z[d0+4], z[d0+5]);
    u.w = pack2(z[d0+6], z[d0+7]);
    *(uint4*)(void*)(orow + d0) = u;
  }
}

// ---------------- K3: depthwise 3x3 conv + BN + GELU, 8 channels/thread ----------------
__global__ __launch_bounds__(256) void k_conv(const ushortT* __restrict__ v1,
                                              const ushortT* __restrict__ dwt,
                                              const float* __restrict__ cparam,
                                              ushortT* __restrict__ cx){
  int tid = blockIdx.x*256 + threadIdx.x;     // SZ/8 total
  int grp = tid % 24;
  int pix = tid / 24;
  int j = pix & (WW-1);
  int rest = pix >> 7;
  int i = rest & (HH-1);
  int b = rest >> 7;
  int c0 = grp*8;
  uint4 wreg[9];
  #pragma unroll
  for (int k=0;k<9;k++) wreg[k] = *(const uint4*)(const void*)(dwt + k*CC + c0);
  float acc[8];
  #pragma unroll
  for (int t2=0;t2<8;t2++) acc[t2]=0.f;
  #pragma unroll
  for (int ki=0;ki<3;ki++){
    int ii = i + ki - 1;
    if (ii < 0 || ii >= HH) continue;
    #pragma unroll
    for (int kj=0;kj<3;kj++){
      int jj = j + kj - 1;
      if (jj < 0 || jj >= WW) continue;
      uint4 uv = *(const uint4*)(const void*)(v1 + (((size_t)b*LL) + (size_t)ii*WW + jj)*CC + c0);
      float fv[8], fw[8];
      unpack8(uv, fv);
      unpack8(wreg[ki*3+kj], fw);
      #pragma unroll
      for (int t2=0;t2<8;t2++) acc[t2] = fmaf(fv[t2], fw[t2], acc[t2]);
    }
  }
  float4 s0 = *(const float4*)(cparam + c0);
  float4 s1 = *(const float4*)(cparam + c0 + 4);
  float4 o0 = *(const float4*)(cparam + CC + c0);
  float4 o1 = *(const float4*)(cparam + CC + c0 + 4);
  float scv[8] = {s0.x,s0.y,s0.z,s0.w,s1.x,s1.y,s1.z,s1.w};
  float ofv[8] = {o0.x,o0.y,o0.z,o0.w,o1.x,o1.y,o1.z,o1.w};
  unsigned ou[4];
  #pragma unroll
  for (int t2=0;t2<4;t2++){
    float y0 = gelu_exact(acc[2*t2]  *scv[2*t2]   + ofv[2*t2]);
    float y1 = gelu_exact(acc[2*t2+1]*scv[2*t2+1] + ofv[2*t2+1]);
    ou[t2] = pack2(y0, y1);
  }
  uint4 res; res.x=ou[0]; res.y=ou[1]; res.z=ou[2]; res.w=ou[3];
  *(uint4*)(void*)(cx + (size_t)pix*CC + c0) = res;
}

// ---------------- K4: per-pixel SE gate via MFMA ----------------
__global__ __launch_bounds__(256) void k_gate(const ushortT* __restrict__ att,
                                              const ushortT* __restrict__ wsi,
                                              const float* __restrict__ gparam,
                                              const float* __restrict__ si_b2,
                                              float* __restrict__ gate){
  int w = threadIdx.x >> 6, l = threadIdx.x & 63;
  int row0 = blockIdx.x*128 + w*32;
  int lr = l & 15;
  int lk = (l >> 4) * 8;
  f32x4 acc[2][6];
  #pragma unroll
  for (int rt=0; rt<2; rt++)
    #pragma unroll
    for (int n=0; n<6; n++) acc[rt][n] = (f32x4){0.f,0.f,0.f,0.f};
  #pragma unroll
  for (int ks = 0; ks < 6; ks++){
    int k0 = ks*32 + lk;
    bf16x8 a0 = *(const bf16x8*)(const void*)(att + (size_t)(row0 + lr)*CC + k0);
    bf16x8 a1 = *(const bf16x8*)(const void*)(att + (size_t)(row0 + 16 + lr)*CC + k0);
    #pragma unroll
    for (int n=0; n<6; n++){
      bf16x8 bfr = *(const bf16x8*)(const void*)(wsi + (size_t)(n*16 + lr)*CC + k0);
      acc[0][n] = __builtin_amdgcn_mfma_f32_16x16x32_bf16(a0, bfr, acc[0][n], 0, 0, 0);
      acc[1][n] = __builtin_amdgcn_mfma_f32_16x16x32_bf16(a1, bfr, acc[1][n], 0, 0, 0);
    }
  }
  int crow = (l >> 4) * 4, ccol = l & 15;
  float sc6[6], cb6[6], w26[6];
  #pragma unroll
  for (int n=0; n<6; n++){
    int o = n*16 + ccol;
    sc6[n] = gparam[o];
    cb6[n] = gparam[CBh + o];
    w26[n] = gparam[2*CBh + o];
  }
  float sb2 = si_b2[0];
  float ps[2][4];
  #pragma unroll
  for (int rt=0; rt<2; rt++)
    #pragma unroll
    for (int r=0; r<4; r++) ps[rt][r] = 0.f;
  #pragma unroll
  for (int rt=0; rt<2; rt++)
    #pragma unroll
    for (int n=0; n<6; n++)
      #pragma unroll
      for (int r=0; r<4; r++){
        float x = acc[rt][n][r]*sc6[n] + cb6[n];
        ps[rt][r] += gelu_exact(x) * w26[n];
      }
  #pragma unroll
  for (int rt=0; rt<2; rt++)
    #pragma unroll
    for (int r=0; r<4; r++){
      float v = ps[rt][r];
      #pragma unroll
      for (int off = 1; off < 16; off <<= 1) v += __shfl_xor(v, off, 64);
      ps[rt][r] = v;
    }
  if (ccol == 0){
    #pragma unroll
    for (int rt=0; rt<2; rt++)
      #pragma unroll
      for (int r=0; r<4; r++){
        int m = row0 + rt*16 + crow + r;
        gate[m] = 1.0f / (1.0f + __expf(-(ps[rt][r] + sb2)));
      }
  }
}

// ---------------- K5: proj GEMM via MFMA, whole B in LDS, 16-row waves, fused gate, hoisted loads ----------------
__global__ __launch_bounds__(512, 2) void k_proj(const ushortT* __restrict__ att, const ushortT* __restrict__ cx,
                                                 const float* __restrict__ gate,
                                                 const ushortT* __restrict__ wp, const float* __restrict__ pbias,
                                                 float* __restrict__ out){
  __shared__ char Bs[CC*CC*2];     // 73728 B
  stage_B512(wp, Bs);

  int w = threadIdx.x >> 6, l = threadIdx.x & 63;
  int row0 = blockIdx.x*128 + w*16;
  int lr = l & 15;
  int hk = l >> 4;
  float gv = gate[row0 + lr];
  size_t base = (size_t)(row0 + lr)*CC + hk*8;

  uint4 ba[6], bc[6];          // 48 VGPRs, 12 independent loads in flight
  #pragma unroll
  for (int ks = 0; ks < 6; ks++){
    ba[ks] = *(const uint4*)(const void*)(att + base + ks*32);
    bc[ks] = *(const uint4*)(const void*)(cx  + base + ks*32);
  }
  f32x4 acc[12];
  #pragma unroll
  for (int n=0; n<12; n++) acc[n] = (f32x4){0.f,0.f,0.f,0.f};
  __syncthreads();

  #pragma unroll
  for (int ks = 0; ks < 6; ks++){
    float fa[8], fc[8];
    unpack8(ba[ks], fa); unpack8(bc[ks], fc);
    #pragma unroll
    for (int j=0;j<8;j++) fa[j] = fmaf(gv, fc[j], fa[j]);
    ABu a;
    a.u[0] = cvt2(fa[0], fa[1]); a.u[1] = cvt2(fa[2], fa[3]);
    a.u[2] = cvt2(fa[4], fa[5]); a.u[3] = cvt2(fa[6], fa[7]);
    int kb = ks*64 + hk*16;
    #pragma unroll
    for (int n=0; n<12; n++){
      bf16x8 bfr = ldsB(Bs, n*16 + lr, kb);
      acc[n] = __builtin_amdgcn_mfma_f32_16x16x32_bf16(a.v, bfr, acc[n], 0, 0, 0);
    }
  }
  int crow = hk*4, ccol = lr;
  #pragma unroll
  for (int n=0; n<12; n++){
    float bv = pbias[n*16 + ccol];
    #pragma unroll
    for (int r=0; r<4; r++){
      int m = row0 + crow + r;
      out[(size_t)m*CC + n*16 + ccol] = acc[n][r] + bv;
    }
  }
}

extern "C" void kernel_launch(void* const* d_in, const int* in_sizes, int n_in,
                              void* d_out, int out_size, void* d_ws, size_t ws_size,
                              hipStream_t stream){
  const float* x1    = (const float*)d_in[0];
  const float* x2    = (const float*)d_in[1];
  const float* qkv_w = (const float*)d_in[2];
  const float* proj_w= (const float*)d_in[3];
  const float* proj_b= (const float*)d_in[4];
  const float* pw    = (const float*)d_in[5];
  const float* pb    = (const float*)d_in[6];
  const float* g1    = (const float*)d_in[7];
  const float* b1    = (const float*)d_in[8];
  const float* w1    = (const float*)d_in[9];
  const float* c1    = (const float*)d_in[10];
  const float* g2    = (const float*)d_in[11];
  const float* b2    = (const float*)d_in[12];
  const float* w2    = (const float*)d_in[13];
  const float* c2    = (const float*)d_in[14];
  const float* g3    = (const float*)d_in[15];
  const float* b3    = (const float*)d_in[16];
  const float* w3    = (const float*)d_in[17];
  const float* c3    = (const float*)d_in[18];
  const float* dw_w  = (const float*)d_in[19];
  const float* dw_b  = (const float*)d_in[20];
  const float* bn1_g = (const float*)d_in[21];
  const float* bn1_b = (const float*)d_in[22];
  const float* bn1_m = (const float*)d_in[23];
  const float* bn1_v = (const float*)d_in[24];
  const float* si_w1 = (const float*)d_in[25];
  const float* si_b1 = (const float*)d_in[26];
  const float* bn2_g = (const float*)d_in[27];
  const float* bn2_b = (const float*)d_in[28];
  const float* bn2_m = (const float*)d_in[29];
  const float* bn2_v = (const float*)d_in[30];
  const float* si_w2 = (const float*)d_in[31];
  const float* si_b2 = (const float*)d_in[32];
  float* out = (float*)d_out;

  char* ws = (char*)d_ws;
  const size_t SZ  = (size_t)BDIM * LL * CC;   // 25,165,824 elements
  const size_t SZB = SZ * 2;                   // bf16 bytes per buffer
  ushortT* q1   = (ushortT*)(ws);
  ushortT* v1   = (ushortT*)(ws + SZB);
  ushortT* k2   = (ushortT*)(ws + 2*SZB);
  ushortT* att  = (ushortT*)(ws + 3*SZB);
  float*   gate = (float*)  (ws + 4*SZB);
  float*   pos  = (float*)  (ws + 4*SZB + (size_t)BDIM*LL*sizeof(float));
  ushortT* wbf  = (ushortT*)(ws + 4*SZB + (size_t)BDIM*LL*sizeof(float) + 16384);
  ushortT* wproj = wbf + WQKV_ELEMS;
  ushortT* wsi   = wproj + WPROJ_ELEMS;
  float*   gparam = (float*)(wbf + WQKV_ELEMS + WPROJ_ELEMS + WSI_ELEMS);
  float*   cparam = gparam + 3*CBh;
  ushortT* dwt    = (ushortT*)(cparam + 2*CC);
  ushortT* convx = q1;   // q1 dead after attention

  k_pos<<<dim3(2), dim3(256), 0, stream>>>(pw,pb,g1,b1,w1,c1,g2,b2,w2,c2,g3,b3,w3,c3,pos);
  k_cvtw<<<dim3((WALL_PAIRS+255)/256), dim3(256), 0, stream>>>(qkv_w, proj_w, si_w1,
      si_b1, bn2_g, bn2_b, bn2_m, bn2_v, si_w2,
      dw_w, dw_b, bn1_g, bn1_b, bn1_m, bn1_v, wbf, gparam, cparam, dwt);
  k_qkv<<<dim3(1024,3), dim3(512), 0, stream>>>(x1, x2, wbf, q1, k2, v1);
  k_attn<4,16><<<dim3(2048), dim3(256), 0, stream>>>(q1, k2, v1, pos, att);
  k_attn<16,4><<<dim3(2048), dim3(256), 0, stream>>>(q1, k2, v1, pos, att);
  k_conv<<<dim3((unsigned)(SZ/8/256)), dim3(256), 0, stream>>>(v1, dwt, cparam, convx);
  k_gate<<<dim3(1024), dim3(256), 0, stream>>>(att, wsi, gparam, si_b2, gate);
  k_proj<<<dim3(1024), dim3(512), 0, stream>>>(att, convx, gate, wproj, proj_b, out);
}

// Round 13
// 325.176 us; speedup vs baseline: 2.6614x; 1.2650x over previous
//
#include <hip/hip_runtime.h>
#include <hip/hip_bf16.h>
#include <math.h>

#define BDIM 8
#define HH 128
#define WW 128
#define LL (HH*WW)          // 16384
#define CC 192
#define CBh 96
#define HBn 4
#define HDd 24
#define PD 6
#define RTAB 217            // (2*4-1)*(2*16-1) for both branches

typedef unsigned short ushortT;
typedef __bf16 bf16x8 __attribute__((ext_vector_type(8)));
typedef float f32x4 __attribute__((ext_vector_type(4)));

__device__ __forceinline__ float b2f(ushortT u){
  union { float f; unsigned u; } x; x.u = ((unsigned)u) << 16; return x.f;
}
__device__ __forceinline__ ushortT f2b(float f){
  union { float f; unsigned u; } x; x.f = f;
  unsigned r = x.u + 0x7fffu + ((x.u >> 16) & 1u);
  return (ushortT)(r >> 16);
}
__device__ __forceinline__ float lo16(unsigned u){ union { float f; unsigned u; } x; x.u = u << 16; return x.f; }
__device__ __forceinline__ float hi16(unsigned u){ union { float f; unsigned u; } x; x.u = u & 0xffff0000u; return x.f; }
__device__ __forceinline__ unsigned pack2(float a, float b){
  return (unsigned)f2b(a) | ((unsigned)f2b(b) << 16);
}
__device__ __forceinline__ void unpack8(uint4 u, float* f){
  f[0]=lo16(u.x); f[1]=hi16(u.x); f[2]=lo16(u.y); f[3]=hi16(u.y);
  f[4]=lo16(u.z); f[5]=hi16(u.z); f[6]=lo16(u.w); f[7]=hi16(u.w);
}
// v_cvt_pk_bf16_f32 via HIP intrinsic (RNE)
__device__ __forceinline__ unsigned cvt2(float a, float b){
  __hip_bfloat162 h = __float22bfloat162_rn(float2{a, b});
  union { __hip_bfloat162 h; unsigned u; } c; c.h = h; return c.u;
}
__device__ __forceinline__ float gelu_exact(float x){
  return 0.5f * x * (1.0f + erff(x * 0.70710678118654752f));
}

union ABu { unsigned u[4]; bf16x8 v; };

// ---- LDS weight staging: full 192x192 bf16 slice (73728 B), XOR-swizzled ----
// byte ^= ((row&7)<<4): consecutive lanes hit consecutive 16B slots (measured
// 0 conflicts in r6/r8; the 64B-stride variant measured 3.5M — keep THIS layout).
__device__ __forceinline__ void stage_B512(const ushortT* __restrict__ Wsrc, char* lds){
  int t = threadIdx.x;
  #pragma unroll
  for (int i = 0; i < 9; i++){
    int c = t + i*512;                 // 16B-chunk index, 4608 total
    int n = c / 24, kc = c - n*24;     // row, chunk-in-row
    uint4 v = *(const uint4*)(const void*)(Wsrc + n*CC + kc*8);
    int byte = n*384 + kc*16;
    byte ^= ((n & 7) << 4);
    *(uint4*)(lds + byte) = v;
  }
}
__device__ __forceinline__ bf16x8 ldsB(const char* lds, int row, int kbyte){
  int byte = row*384 + kbyte;
  byte ^= ((row & 7) << 4);
  return *(const bf16x8*)(lds + byte);
}

// ---------------- K0: dynamic position-bias MLP -> pos[2][217][4] ----------------
__device__ __forceinline__ void ln_relu6(float* p, const float* g, const float* b){
  float m = 0.f;
  #pragma unroll
  for (int j=0;j<PD;j++) m += p[j];
  m *= (1.0f/PD);
  float v = 0.f;
  #pragma unroll
  for (int j=0;j<PD;j++){ float d = p[j]-m; v += d*d; }
  v *= (1.0f/PD);
  float is = rsqrtf(v + 1e-5f);
  #pragma unroll
  for (int j=0;j<PD;j++){ float t = (p[j]-m)*is*g[j] + b[j]; p[j] = t > 0.f ? t : 0.f; }
}
__device__ __forceinline__ void mm6(float* p, const float* w, const float* c){
  float q[PD];
  #pragma unroll
  for (int j=0;j<PD;j++){
    float a = c[j];
    #pragma unroll
    for (int i=0;i<PD;i++) a += p[i]*w[j*PD+i];
    q[j] = a;
  }
  #pragma unroll
  for (int j=0;j<PD;j++) p[j] = q[j];
}

__global__ void k_pos(const float* __restrict__ pw, const float* __restrict__ pb,
                      const float* __restrict__ g1, const float* __restrict__ b1,
                      const float* __restrict__ w1, const float* __restrict__ c1,
                      const float* __restrict__ g2, const float* __restrict__ b2,
                      const float* __restrict__ w2, const float* __restrict__ c2,
                      const float* __restrict__ g3, const float* __restrict__ b3,
                      const float* __restrict__ w3, const float* __restrict__ c3,
                      float* __restrict__ pos){
  int br = blockIdx.x;
  int r = threadIdx.x;
  if (r >= RTAB) return;
  int Hsp = br ? 16 : 4, Wsp = br ? 4 : 16;
  int W2 = 2*Wsp - 1;
  float bi0 = (float)(r / W2 - (Hsp-1));
  float bi1 = (float)(r % W2 - (Wsp-1));
  const float* PW = pw + br*PD*2;
  const float* PB = pb + br*PD;
  float p[PD];
  #pragma unroll
  for (int j=0;j<PD;j++) p[j] = PW[j*2]*bi0 + PW[j*2+1]*bi1 + PB[j];
  ln_relu6(p, g1+br*PD, b1+br*PD);
  mm6(p, w1+br*PD*PD, c1+br*PD);
  ln_relu6(p, g2+br*PD, b2+br*PD);
  mm6(p, w2+br*PD*PD, c2+br*PD);
  ln_relu6(p, g3+br*PD, b3+br*PD);
  const float* W3 = w3 + br*HBn*PD;
  const float* C3 = c3 + br*HBn;
  #pragma unroll
  for (int h=0;h<HBn;h++){
    float a = C3[h];
    #pragma unroll
    for (int i=0;i<PD;i++) a += p[i]*W3[h*PD+i];
    pos[((size_t)br*RTAB + r)*HBn + h] = a;
  }
}

// ---------------- K-cvt: convert weights to bf16; fold BN params; build conv tables ----------------
#define WQKV_ELEMS (3*CC*CC)                     // 110592
#define WPROJ_ELEMS (CC*CC)                      // 36864
#define WSI_ELEMS (CC*CBh)                       // 18432
#define WALL_PAIRS ((WQKV_ELEMS+WPROJ_ELEMS+WSI_ELEMS)/2)  // 82944

__global__ void k_cvtw(const float* __restrict__ qkv_w, const float* __restrict__ proj_w,
                       const float* __restrict__ si_w1,
                       const float* __restrict__ si_b1,
                       const float* __restrict__ g, const float* __restrict__ bb,
                       const float* __restrict__ mn, const float* __restrict__ vv,
                       const float* __restrict__ si_w2,
                       const float* __restrict__ dw_w, const float* __restrict__ dw_b,
                       const float* __restrict__ bn1_g, const float* __restrict__ bn1_b,
                       const float* __restrict__ bn1_m, const float* __restrict__ bn1_v,
                       ushortT* __restrict__ wb, float* __restrict__ gparam,
                       float* __restrict__ cparam, ushortT* __restrict__ dwt){
  int t = threadIdx.x;
  if (blockIdx.x == 0 && t < CBh){
    float sc = g[t]*rsqrtf(vv[t]+1e-5f);
    gparam[t]        = sc;                                   // scale
    gparam[CBh+t]    = (si_b1[t]-mn[t])*sc + bb[t];          // folded bias
    gparam[2*CBh+t]  = si_w2[t];                             // w2
  }
  if (blockIdx.x == 1){
    if (t < CC){
      float sc = bn1_g[t]*rsqrtf(bn1_v[t]+1e-5f);
      cparam[t]      = sc;
      cparam[CC+t]   = (dw_b[t]-bn1_m[t])*sc + bn1_b[t];
    }
    for (int i = t; i < 9*CC; i += 256){
      int k = i / CC, c = i - k*CC;
      dwt[i] = f2b(dw_w[c*9 + k]);
    }
  }
  int i = blockIdx.x*256 + t;
  if (i >= WALL_PAIRS) return;
  int e = i*2;
  float a, b;
  if (e < WQKV_ELEMS){ a = qkv_w[e]; b = qkv_w[e+1]; }
  else if (e < WQKV_ELEMS+WPROJ_ELEMS){ a = proj_w[e-WQKV_ELEMS]; b = proj_w[e-WQKV_ELEMS+1]; }
  else { a = si_w1[e-WQKV_ELEMS-WPROJ_ELEMS]; b = si_w1[e-WQKV_ELEMS-WPROJ_ELEMS+1]; }
  *(unsigned*)(void*)(wb + e) = cvt2(a, b);
}

// ---------------- K1: QKV GEMM via MFMA, whole B in LDS, 16-row waves (r8-proven) ----------------
__global__ __launch_bounds__(512, 4) void k_qkv(const float* __restrict__ x1, const float* __restrict__ x2,
                                                const ushortT* __restrict__ wb,
                                                ushortT* __restrict__ q1, ushortT* __restrict__ k2,
                                                ushortT* __restrict__ v1){
  __shared__ char Bs[CC*CC*2];     // 73728 B
  int z = blockIdx.y;
  const float* src = (z == 1) ? x2 : x1;
  ushortT* dst = (z == 0) ? q1 : ((z == 1) ? k2 : v1);
  stage_B512(wb + (size_t)z*CC*CC, Bs);

  int w = threadIdx.x >> 6, l = threadIdx.x & 63;
  int row0 = blockIdx.x*128 + w*16;
  int lr = l & 15;            // frag row (A) / col (B)
  int hk = l >> 4;            // k-phase
  f32x4 acc[12];
  #pragma unroll
  for (int n=0; n<12; n++) acc[n] = (f32x4){0.f,0.f,0.f,0.f};

  const float* ap = src + (size_t)(row0 + lr)*CC + hk*8;
  __syncthreads();

  #pragma unroll
  for (int ks = 0; ks < 6; ks++){
    float4 p0 = *(const float4*)(ap + ks*32);
    float4 p1 = *(const float4*)(ap + ks*32 + 4);
    ABu a;
    a.u[0] = cvt2(p0.x, p0.y); a.u[1] = cvt2(p0.z, p0.w);
    a.u[2] = cvt2(p1.x, p1.y); a.u[3] = cvt2(p1.z, p1.w);
    int kb = ks*64 + hk*16;
    #pragma unroll
    for (int n=0; n<12; n++){
      bf16x8 bfr = ldsB(Bs, n*16 + lr, kb);
      acc[n] = __builtin_amdgcn_mfma_f32_16x16x32_bf16(a.v, bfr, acc[n], 0, 0, 0);
    }
  }
  int crow = hk*4, ccol = lr;
  #pragma unroll
  for (int n=0; n<12; n++)
    #pragma unroll
    for (int r=0; r<4; r++){
      int m = row0 + crow + r;
      dst[(size_t)m*CC + n*16 + ccol] = f2b(acc[n][r]);
    }
}

// ---------------- K2: windowed attention via MFMA ----------------
// Block = one window (64 pixels), 4 waves = 4 heads. Q,K staged padded bf16
// [4][64][40] (80B rows: b128 frag reads 2-way = free); V transposed [4][32][72]
// (144B rows: 2-way free). P (softmaxed scores, bf16) overlays dead Q/K at
// [4][64][72]. All MFMA layouts identical to the verified GEMM kernels.
template<int HSP, int WSP>
__global__ __launch_bounds__(256, 2) void k_attn(const ushortT* __restrict__ q1, const ushortT* __restrict__ k2,
                                                 const ushortT* __restrict__ v1, const float* __restrict__ pos,
                                                 ushortT* __restrict__ att){
  constexpr int BR = (HSP == 4) ? 0 : 1;
  constexpr int NWH = HH / HSP, NWW = WW / WSP;
  constexpr int CH0 = BR * CBh;
  constexpr float SCALE = 0.20412414523193154f;   // 1/sqrt(24)
  __shared__ ushortT poolA[20480];   // Q @0 [4][64][40]; K @10240; later P [4][64][72]
  __shared__ ushortT VTs[9216];      // [4][32][72]
  __shared__ float ps[RTAB*HBn];
  int t = threadIdx.x;
  int wid = blockIdx.x;
  int b = wid / (NWH*NWW);
  int rem = wid - b*(NWH*NWW);
  int wr = rem / NWW, wc = rem - wr*NWW;

  for (int i = t; i < RTAB*HBn; i += 256) ps[i] = pos[(size_t)BR*RTAB*HBn + i];

  #pragma unroll
  for (int it = 0; it < 3; it++){
    int e = t + it*256;                    // 768 = 64 pix * 12 chunks
    int p = e / 12, seg = e - p*12;
    int h = seg / 3, c0 = (seg - h*3)*8;   // 24ch/head = 3 chunks, aligned
    int ii = p / WSP, jj = p - ii*WSP;
    size_t g = ((size_t)b*LL + (size_t)(wr*HSP + ii)*WW + wc*WSP + jj)*CC + CH0 + h*24 + c0;
    uint4 uq = *(const uint4*)(const void*)(q1 + g);
    uint4 uk = *(const uint4*)(const void*)(k2 + g);
    uint4 uv = *(const uint4*)(const void*)(v1 + g);
    *(uint4*)(void*)&poolA[(h*64 + p)*40 + c0] = uq;
    *(uint4*)(void*)&poolA[10240 + (h*64 + p)*40 + c0] = uk;
    union { uint4 u; ushortT s[8]; } vu; vu.u = uv;
    #pragma unroll
    for (int j = 0; j < 8; j++)
      VTs[(h*32 + c0 + j)*72 + p] = vu.s[j];
  }
  {
    int h = t >> 6, p = t & 63;            // zero-pad channels 24..31
    uint4 z4; z4.x = z4.y = z4.z = z4.w = 0u;
    *(uint4*)(void*)&poolA[(h*64 + p)*40 + 24] = z4;
    *(uint4*)(void*)&poolA[10240 + (h*64 + p)*40 + 24] = z4;
  }
  __syncthreads();

  int w = t >> 6, l = t & 63;
  int lo = l & 15, hi = l >> 4;

  bf16x8 qa[4], kb[4];
  #pragma unroll
  for (int mt = 0; mt < 4; mt++)
    qa[mt] = *(const bf16x8*)(const void*)&poolA[(w*64 + mt*16 + lo)*40 + hi*8];
  #pragma unroll
  for (int nt = 0; nt < 4; nt++)
    kb[nt] = *(const bf16x8*)(const void*)&poolA[10240 + (w*64 + nt*16 + lo)*40 + hi*8];
  __syncthreads();   // all frags in regs; poolA becomes P

  f32x4 sacc[4][4];
  #pragma unroll
  for (int mt = 0; mt < 4; mt++)
    #pragma unroll
    for (int nt = 0; nt < 4; nt++) sacc[mt][nt] = (f32x4){0.f,0.f,0.f,0.f};
  #pragma unroll
  for (int mt = 0; mt < 4; mt++)
    #pragma unroll
    for (int nt = 0; nt < 4; nt++)
      sacc[mt][nt] = __builtin_amdgcn_mfma_f32_16x16x32_bf16(qa[mt], kb[nt], sacc[mt][nt], 0, 0, 0);

  float invl[4][4];
  #pragma unroll
  for (int mt = 0; mt < 4; mt++){
    #pragma unroll
    for (int r = 0; r < 4; r++){
      int i = mt*16 + hi*4 + r;
      int i1 = i / WSP, j1 = i - i1*WSP;
      float sv[4];
      #pragma unroll
      for (int nt = 0; nt < 4; nt++){
        int j = nt*16 + lo;
        int i2 = j / WSP, j2 = j - i2*WSP;
        int ridx = (i1 - i2 + HSP - 1)*(2*WSP - 1) + (j1 - j2 + WSP - 1);
        sv[nt] = sacc[mt][nt][r]*SCALE + ps[ridx*HBn + w];
      }
      float mx = fmaxf(fmaxf(sv[0], sv[1]), fmaxf(sv[2], sv[3]));
      #pragma unroll
      for (int off = 1; off < 16; off <<= 1) mx = fmaxf(mx, __shfl_xor(mx, off, 64));
      float sum = 0.f;
      #pragma unroll
      for (int nt = 0; nt < 4; nt++){ sv[nt] = __expf(sv[nt] - mx); sum += sv[nt]; }
      #pragma unroll
      for (int off = 1; off < 16; off <<= 1) sum += __shfl_xor(sum, off, 64);
      invl[mt][r] = 1.0f / sum;
      #pragma unroll
      for (int nt = 0; nt < 4; nt++)
        poolA[(w*64 + i)*72 + nt*16 + lo] = f2b(sv[nt]);
    }
  }
  __syncthreads();

  bf16x8 pa[4][2], vb[2][2];
  #pragma unroll
  for (int mt = 0; mt < 4; mt++)
    #pragma unroll
    for (int kt = 0; kt < 2; kt++)
      pa[mt][kt] = *(const bf16x8*)(const void*)&poolA[(w*64 + mt*16 + lo)*72 + kt*32 + hi*8];
  #pragma unroll
  for (int nt2 = 0; nt2 < 2; nt2++)
    #pragma unroll
    for (int kt = 0; kt < 2; kt++)
      vb[nt2][kt] = *(const bf16x8*)(const void*)&VTs[(w*32 + nt2*16 + lo)*72 + kt*32 + hi*8];

  f32x4 oacc[4][2];
  #pragma unroll
  for (int mt = 0; mt < 4; mt++)
    #pragma unroll
    for (int nt2 = 0; nt2 < 2; nt2++) oacc[mt][nt2] = (f32x4){0.f,0.f,0.f,0.f};
  #pragma unroll
  for (int mt = 0; mt < 4; mt++)
    #pragma unroll
    for (int nt2 = 0; nt2 < 2; nt2++)
      #pragma unroll
      for (int kt = 0; kt < 2; kt++)
        oacc[mt][nt2] = __builtin_amdgcn_mfma_f32_16x16x32_bf16(pa[mt][kt], vb[nt2][kt], oacc[mt][nt2], 0, 0, 0);

  #pragma unroll
  for (int mt = 0; mt < 4; mt++)
    #pragma unroll
    for (int nt2 = 0; nt2 < 2; nt2++){
      int d = nt2*16 + lo;
      if (nt2 == 1 && lo >= 8) continue;   // d >= 24: padded garbage column
      #pragma unroll
      for (int r = 0; r < 4; r++){
        int i = mt*16 + hi*4 + r;
        int ii = i / WSP, jj = i - ii*WSP;
        size_t g = ((size_t)b*LL + (size_t)(wr*HSP + ii)*WW + wc*WSP + jj)*CC + CH0 + w*24 + d;
        att[g] = f2b(oacc[mt][nt2][r] * invl[mt][r]);
      }
    }
}

// ---------------- K3: depthwise 3x3 conv + BN + GELU, 8 channels/thread ----------------
__global__ __launch_bounds__(256) void k_conv(const ushortT* __restrict__ v1,
                                              const ushortT* __restrict__ dwt,
                                              const float* __restrict__ cparam,
                                              ushortT* __restrict__ cx){
  int tid = blockIdx.x*256 + threadIdx.x;     // SZ/8 total
  int grp = tid % 24;
  int pix = tid / 24;
  int j = pix & (WW-1);
  int rest = pix >> 7;
  int i = rest & (HH-1);
  int b = rest >> 7;
  int c0 = grp*8;
  uint4 wreg[9];
  #pragma unroll
  for (int k=0;k<9;k++) wreg[k] = *(const uint4*)(const void*)(dwt + k*CC + c0);
  float acc[8];
  #pragma unroll
  for (int t2=0;t2<8;t2++) acc[t2]=0.f;
  #pragma unroll
  for (int ki=0;ki<3;ki++){
    int ii = i + ki - 1;
    if (ii < 0 || ii >= HH) continue;
    #pragma unroll
    for (int kj=0;kj<3;kj++){
      int jj = j + kj - 1;
      if (jj < 0 || jj >= WW) continue;
      uint4 uv = *(const uint4*)(const void*)(v1 + (((size_t)b*LL) + (size_t)ii*WW + jj)*CC + c0);
      float fv[8], fw[8];
      unpack8(uv, fv);
      unpack8(wreg[ki*3+kj], fw);
      #pragma unroll
      for (int t2=0;t2<8;t2++) acc[t2] = fmaf(fv[t2], fw[t2], acc[t2]);
    }
  }
  float4 s0 = *(const float4*)(cparam + c0);
  float4 s1 = *(const float4*)(cparam + c0 + 4);
  float4 o0 = *(const float4*)(cparam + CC + c0);
  float4 o1 = *(const float4*)(cparam + CC + c0 + 4);
  float scv[8] = {s0.x,s0.y,s0.z,s0.w,s1.x,s1.y,s1.z,s1.w};
  float ofv[8] = {o0.x,o0.y,o0.z,o0.w,o1.x,o1.y,o1.z,o1.w};
  unsigned ou[4];
  #pragma unroll
  for (int t2=0;t2<4;t2++){
    float y0 = gelu_exact(acc[2*t2]  *scv[2*t2]   + ofv[2*t2]);
    float y1 = gelu_exact(acc[2*t2+1]*scv[2*t2+1] + ofv[2*t2+1]);
    ou[t2] = pack2(y0, y1);
  }
  uint4 res; res.x=ou[0]; res.y=ou[1]; res.z=ou[2]; res.w=ou[3];
  *(uint4*)(void*)(cx + (size_t)pix*CC + c0) = res;
}

// ---------------- K4: per-pixel SE gate via MFMA ----------------
__global__ __launch_bounds__(256) void k_gate(const ushortT* __restrict__ att,
                                              const ushortT* __restrict__ wsi,
                                              const float* __restrict__ gparam,
                                              const float* __restrict__ si_b2,
                                              float* __restrict__ gate){
  int w = threadIdx.x >> 6, l = threadIdx.x & 63;
  int row0 = blockIdx.x*128 + w*32;
  int lr = l & 15;
  int lk = (l >> 4) * 8;
  f32x4 acc[2][6];
  #pragma unroll
  for (int rt=0; rt<2; rt++)
    #pragma unroll
    for (int n=0; n<6; n++) acc[rt][n] = (f32x4){0.f,0.f,0.f,0.f};
  #pragma unroll
  for (int ks = 0; ks < 6; ks++){
    int k0 = ks*32 + lk;
    bf16x8 a0 = *(const bf16x8*)(const void*)(att + (size_t)(row0 + lr)*CC + k0);
    bf16x8 a1 = *(const bf16x8*)(const void*)(att + (size_t)(row0 + 16 + lr)*CC + k0);
    #pragma unroll
    for (int n=0; n<6; n++){
      bf16x8 bfr = *(const bf16x8*)(const void*)(wsi + (size_t)(n*16 + lr)*CC + k0);
      acc[0][n] = __builtin_amdgcn_mfma_f32_16x16x32_bf16(a0, bfr, acc[0][n], 0, 0, 0);
      acc[1][n] = __builtin_amdgcn_mfma_f32_16x16x32_bf16(a1, bfr, acc[1][n], 0, 0, 0);
    }
  }
  int crow = (l >> 4) * 4, ccol = l & 15;
  float sc6[6], cb6[6], w26[6];
  #pragma unroll
  for (int n=0; n<6; n++){
    int o = n*16 + ccol;
    sc6[n] = gparam[o];
    cb6[n] = gparam[CBh + o];
    w26[n] = gparam[2*CBh + o];
  }
  float sb2 = si_b2[0];
  float ps[2][4];
  #pragma unroll
  for (int rt=0; rt<2; rt++)
    #pragma unroll
    for (int r=0; r<4; r++) ps[rt][r] = 0.f;
  #pragma unroll
  for (int rt=0; rt<2; rt++)
    #pragma unroll
    for (int n=0; n<6; n++)
      #pragma unroll
      for (int r=0; r<4; r++){
        float x = acc[rt][n][r]*sc6[n] + cb6[n];
        ps[rt][r] += gelu_exact(x) * w26[n];
      }
  #pragma unroll
  for (int rt=0; rt<2; rt++)
    #pragma unroll
    for (int r=0; r<4; r++){
      float v = ps[rt][r];
      #pragma unroll
      for (int off = 1; off < 16; off <<= 1) v += __shfl_xor(v, off, 64);
      ps[rt][r] = v;
    }
  if (ccol == 0){
    #pragma unroll
    for (int rt=0; rt<2; rt++)
      #pragma unroll
      for (int r=0; r<4; r++){
        int m = row0 + rt*16 + crow + r;
        gate[m] = 1.0f / (1.0f + __expf(-(ps[rt][r] + sb2)));
      }
  }
}

// ---------------- K5: proj GEMM via MFMA, whole B in LDS, 16-row waves, fused gate (r8-proven) ----------------
__global__ __launch_bounds__(512, 4) void k_proj(const ushortT* __restrict__ att, const ushortT* __restrict__ cx,
                                                 const float* __restrict__ gate,
                                                 const ushortT* __restrict__ wp, const float* __restrict__ pbias,
                                                 float* __restrict__ out){
  __shared__ char Bs[CC*CC*2];     // 73728 B
  stage_B512(wp, Bs);

  int w = threadIdx.x >> 6, l = threadIdx.x & 63;
  int row0 = blockIdx.x*128 + w*16;
  int lr = l & 15;
  int hk = l >> 4;
  float gv = gate[row0 + lr];
  f32x4 acc[12];
  #pragma unroll
  for (int n=0; n<12; n++) acc[n] = (f32x4){0.f,0.f,0.f,0.f};

  size_t base = (size_t)(row0 + lr)*CC + hk*8;
  __syncthreads();

  #pragma unroll
  for (int ks = 0; ks < 6; ks++){
    uint4 ua = *(const uint4*)(const void*)(att + base + ks*32);
    uint4 uc = *(const uint4*)(const void*)(cx  + base + ks*32);
    float fa[8], fc[8];
    unpack8(ua, fa); unpack8(uc, fc);
    #pragma unroll
    for (int j=0;j<8;j++) fa[j] = fmaf(gv, fc[j], fa[j]);
    ABu a;
    a.u[0] = cvt2(fa[0], fa[1]); a.u[1] = cvt2(fa[2], fa[3]);
    a.u[2] = cvt2(fa[4], fa[5]); a.u[3] = cvt2(fa[6], fa[7]);
    int kb = ks*64 + hk*16;
    #pragma unroll
    for (int n=0; n<12; n++){
      bf16x8 bfr = ldsB(Bs, n*16 + lr, kb);
      acc[n] = __builtin_amdgcn_mfma_f32_16x16x32_bf16(a.v, bfr, acc[n], 0, 0, 0);
    }
  }
  int crow = hk*4, ccol = lr;
  #pragma unroll
  for (int n=0; n<12; n++){
    float bv = pbias[n*16 + ccol];
    #pragma unroll
    for (int r=0; r<4; r++){
      int m = row0 + crow + r;
      out[(size_t)m*CC + n*16 + ccol] = acc[n][r] + bv;
    }
  }
}

extern "C" void kernel_launch(void* const* d_in, const int* in_sizes, int n_in,
                              void* d_out, int out_size, void* d_ws, size_t ws_size,
                              hipStream_t stream){
  const float* x1    = (const float*)d_in[0];
  const float* x2    = (const float*)d_in[1];
  const float* qkv_w = (const float*)d_in[2];
  const float* proj_w= (const float*)d_in[3];
  const float* proj_b= (const float*)d_in[4];
  const float* pw    = (const float*)d_in[5];
  const float* pb    = (const float*)d_in[6];
  const float* g1    = (const float*)d_in[7];
  const float* b1    = (const float*)d_in[8];
  const float* w1    = (const float*)d_in[9];
  const float* c1    = (const float*)d_in[10];
  const float* g2    = (const float*)d_in[11];
  const float* b2    = (const float*)d_in[12];
  const float* w2    = (const float*)d_in[13];
  const float* c2    = (const float*)d_in[14];
  const float* g3    = (const float*)d_in[15];
  const float* b3    = (const float*)d_in[16];
  const float* w3    = (const float*)d_in[17];
  const float* c3    = (const float*)d_in[18];
  const float* dw_w  = (const float*)d_in[19];
  const float* dw_b  = (const float*)d_in[20];
  const float* bn1_g = (const float*)d_in[21];
  const float* bn1_b = (const float*)d_in[22];
  const float* bn1_m = (const float*)d_in[23];
  const float* bn1_v = (const float*)d_in[24];
  const float* si_w1 = (const float*)d_in[25];
  const float* si_b1 = (const float*)d_in[26];
  const float* bn2_g = (const float*)d_in[27];
  const float* bn2_b = (const float*)d_in[28];
  const float* bn2_m = (const float*)d_in[29];
  const float* bn2_v = (const float*)d_in[30];
  const float* si_w2 = (const float*)d_in[31];
  const float* si_b2 = (const float*)d_in[32];
  float* out = (float*)d_out;

  char* ws = (char*)d_ws;
  const size_t SZ  = (size_t)BDIM * LL * CC;   // 25,165,824 elements
  const size_t SZB = SZ * 2;                   // bf16 bytes per buffer
  ushortT* q1   = (ushortT*)(ws);
  ushortT* v1   = (ushortT*)(ws + SZB);
  ushortT* k2   = (ushortT*)(ws + 2*SZB);
  ushortT* att  = (ushortT*)(ws + 3*SZB);
  float*   gate = (float*)  (ws + 4*SZB);
  float*   pos  = (float*)  (ws + 4*SZB + (size_t)BDIM*LL*sizeof(float));
  ushortT* wbf  = (ushortT*)(ws + 4*SZB + (size_t)BDIM*LL*sizeof(float) + 16384);
  ushortT* wproj = wbf + WQKV_ELEMS;
  ushortT* wsi   = wproj + WPROJ_ELEMS;
  float*   gparam = (float*)(wbf + WQKV_ELEMS + WPROJ_ELEMS + WSI_ELEMS);
  float*   cparam = gparam + 3*CBh;
  ushortT* dwt    = (ushortT*)(cparam + 2*CC);
  ushortT* convx = q1;   // q1 dead after attention

  k_pos<<<dim3(2), dim3(256), 0, stream>>>(pw,pb,g1,b1,w1,c1,g2,b2,w2,c2,g3,b3,w3,c3,pos);
  k_cvtw<<<dim3((WALL_PAIRS+255)/256), dim3(256), 0, stream>>>(qkv_w, proj_w, si_w1,
      si_b1, bn2_g, bn2_b, bn2_m, bn2_v, si_w2,
      dw_w, dw_b, bn1_g, bn1_b, bn1_m, bn1_v, wbf, gparam, cparam, dwt);
  k_qkv<<<dim3(1024,3), dim3(512), 0, stream>>>(x1, x2, wbf, q1, k2, v1);
  k_attn<4,16><<<dim3(2048), dim3(256), 0, stream>>>(q1, k2, v1, pos, att);
  k_attn<16,4><<<dim3(2048), dim3(256), 0, stream>>>(q1, k2, v1, pos, att);
  k_conv<<<dim3((unsigned)(SZ/8/256)), dim3(256), 0, stream>>>(v1, dwt, cparam, convx);
  k_gate<<<dim3(1024), dim3(256), 0, stream>>>(att, wsi, gparam, si_b2, gate);
  k_proj<<<dim3(1024), dim3(512), 0, stream>>>(att, convx, gate, wproj, proj_b, out);
}

// Round 14
// 312.623 us; speedup vs baseline: 2.7683x; 1.0402x over previous
//
#include <hip/hip_runtime.h>
#include <hip/hip_bf16.h>
#include <math.h>

#define BDIM 8
#define HH 128
#define WW 128
#define LL (HH*WW)          // 16384
#define CC 192
#define CBh 96
#define HBn 4
#define HDd 24
#define PD 6
#define RTAB 217            // (2*4-1)*(2*16-1) for both branches

typedef unsigned short ushortT;
typedef __bf16 bf16x8 __attribute__((ext_vector_type(8)));
typedef float f32x4 __attribute__((ext_vector_type(4)));

__device__ __forceinline__ float b2f(ushortT u){
  union { float f; unsigned u; } x; x.u = ((unsigned)u) << 16; return x.f;
}
__device__ __forceinline__ ushortT f2b(float f){
  union { float f; unsigned u; } x; x.f = f;
  unsigned r = x.u + 0x7fffu + ((x.u >> 16) & 1u);
  return (ushortT)(r >> 16);
}
__device__ __forceinline__ float lo16(unsigned u){ union { float f; unsigned u; } x; x.u = u << 16; return x.f; }
__device__ __forceinline__ float hi16(unsigned u){ union { float f; unsigned u; } x; x.u = u & 0xffff0000u; return x.f; }
__device__ __forceinline__ unsigned pack2(float a, float b){
  return (unsigned)f2b(a) | ((unsigned)f2b(b) << 16);
}
__device__ __forceinline__ void unpack8(uint4 u, float* f){
  f[0]=lo16(u.x); f[1]=hi16(u.x); f[2]=lo16(u.y); f[3]=hi16(u.y);
  f[4]=lo16(u.z); f[5]=hi16(u.z); f[6]=lo16(u.w); f[7]=hi16(u.w);
}
// v_cvt_pk_bf16_f32 via HIP intrinsic (RNE)
__device__ __forceinline__ unsigned cvt2(float a, float b){
  __hip_bfloat162 h = __float22bfloat162_rn(float2{a, b});
  union { __hip_bfloat162 h; unsigned u; } c; c.h = h; return c.u;
}
__device__ __forceinline__ float gelu_exact(float x){
  return 0.5f * x * (1.0f + erff(x * 0.70710678118654752f));
}

union ABu { unsigned u[4]; bf16x8 v; };

// ---- LDS weight staging: full 192x192 bf16 slice (73728 B), XOR-swizzled ----
// byte ^= ((row&7)<<4): consecutive lanes hit consecutive 16B slots (measured
// 0 conflicts in r6/r8; the 64B-stride variant measured 3.5M — keep THIS layout).
__device__ __forceinline__ void stage_B512(const ushortT* __restrict__ Wsrc, char* lds){
  int t = threadIdx.x;
  #pragma unroll
  for (int i = 0; i < 9; i++){
    int c = t + i*512;                 // 16B-chunk index, 4608 total
    int n = c / 24, kc = c - n*24;     // row, chunk-in-row
    uint4 v = *(const uint4*)(const void*)(Wsrc + n*CC + kc*8);
    int byte = n*384 + kc*16;
    byte ^= ((n & 7) << 4);
    *(uint4*)(lds + byte) = v;
  }
}
__device__ __forceinline__ bf16x8 ldsB(const char* lds, int row, int kbyte){
  int byte = row*384 + kbyte;
  byte ^= ((row & 7) << 4);
  return *(const bf16x8*)(lds + byte);
}

// ---------------- K0: dynamic position-bias MLP -> pos[2][217][4] ----------------
__device__ __forceinline__ void ln_relu6(float* p, const float* g, const float* b){
  float m = 0.f;
  #pragma unroll
  for (int j=0;j<PD;j++) m += p[j];
  m *= (1.0f/PD);
  float v = 0.f;
  #pragma unroll
  for (int j=0;j<PD;j++){ float d = p[j]-m; v += d*d; }
  v *= (1.0f/PD);
  float is = rsqrtf(v + 1e-5f);
  #pragma unroll
  for (int j=0;j<PD;j++){ float t = (p[j]-m)*is*g[j] + b[j]; p[j] = t > 0.f ? t : 0.f; }
}
__device__ __forceinline__ void mm6(float* p, const float* w, const float* c){
  float q[PD];
  #pragma unroll
  for (int j=0;j<PD;j++){
    float a = c[j];
    #pragma unroll
    for (int i=0;i<PD;i++) a += p[i]*w[j*PD+i];
    q[j] = a;
  }
  #pragma unroll
  for (int j=0;j<PD;j++) p[j] = q[j];
}

__global__ void k_pos(const float* __restrict__ pw, const float* __restrict__ pb,
                      const float* __restrict__ g1, const float* __restrict__ b1,
                      const float* __restrict__ w1, const float* __restrict__ c1,
                      const float* __restrict__ g2, const float* __restrict__ b2,
                      const float* __restrict__ w2, const float* __restrict__ c2,
                      const float* __restrict__ g3, const float* __restrict__ b3,
                      const float* __restrict__ w3, const float* __restrict__ c3,
                      float* __restrict__ pos){
  int br = blockIdx.x;
  int r = threadIdx.x;
  if (r >= RTAB) return;
  int Hsp = br ? 16 : 4, Wsp = br ? 4 : 16;
  int W2 = 2*Wsp - 1;
  float bi0 = (float)(r / W2 - (Hsp-1));
  float bi1 = (float)(r % W2 - (Wsp-1));
  const float* PW = pw + br*PD*2;
  const float* PB = pb + br*PD;
  float p[PD];
  #pragma unroll
  for (int j=0;j<PD;j++) p[j] = PW[j*2]*bi0 + PW[j*2+1]*bi1 + PB[j];
  ln_relu6(p, g1+br*PD, b1+br*PD);
  mm6(p, w1+br*PD*PD, c1+br*PD);
  ln_relu6(p, g2+br*PD, b2+br*PD);
  mm6(p, w2+br*PD*PD, c2+br*PD);
  ln_relu6(p, g3+br*PD, b3+br*PD);
  const float* W3 = w3 + br*HBn*PD;
  const float* C3 = c3 + br*HBn;
  #pragma unroll
  for (int h=0;h<HBn;h++){
    float a = C3[h];
    #pragma unroll
    for (int i=0;i<PD;i++) a += p[i]*W3[h*PD+i];
    pos[((size_t)br*RTAB + r)*HBn + h] = a;
  }
}

// ---------------- K-cvt: convert weights to bf16; fold BN params; build conv tables ----------------
#define WQKV_ELEMS (3*CC*CC)                     // 110592
#define WPROJ_ELEMS (CC*CC)                      // 36864
#define WSI_ELEMS (CC*CBh)                       // 18432
#define WALL_PAIRS ((WQKV_ELEMS+WPROJ_ELEMS+WSI_ELEMS)/2)  // 82944

__global__ void k_cvtw(const float* __restrict__ qkv_w, const float* __restrict__ proj_w,
                       const float* __restrict__ si_w1,
                       const float* __restrict__ si_b1,
                       const float* __restrict__ g, const float* __restrict__ bb,
                       const float* __restrict__ mn, const float* __restrict__ vv,
                       const float* __restrict__ si_w2,
                       const float* __restrict__ dw_w, const float* __restrict__ dw_b,
                       const float* __restrict__ bn1_g, const float* __restrict__ bn1_b,
                       const float* __restrict__ bn1_m, const float* __restrict__ bn1_v,
                       ushortT* __restrict__ wb, float* __restrict__ gparam,
                       float* __restrict__ cparam, ushortT* __restrict__ dwt){
  int t = threadIdx.x;
  if (blockIdx.x == 0 && t < CBh){
    float sc = g[t]*rsqrtf(vv[t]+1e-5f);
    gparam[t]        = sc;                                   // scale
    gparam[CBh+t]    = (si_b1[t]-mn[t])*sc + bb[t];          // folded bias
    gparam[2*CBh+t]  = si_w2[t];                             // w2
  }
  if (blockIdx.x == 1){
    if (t < CC){
      float sc = bn1_g[t]*rsqrtf(bn1_v[t]+1e-5f);
      cparam[t]      = sc;
      cparam[CC+t]   = (dw_b[t]-bn1_m[t])*sc + bn1_b[t];
    }
    for (int i = t; i < 9*CC; i += 256){
      int k = i / CC, c = i - k*CC;
      dwt[i] = f2b(dw_w[c*9 + k]);
    }
  }
  int i = blockIdx.x*256 + t;
  if (i >= WALL_PAIRS) return;
  int e = i*2;
  float a, b;
  if (e < WQKV_ELEMS){ a = qkv_w[e]; b = qkv_w[e+1]; }
  else if (e < WQKV_ELEMS+WPROJ_ELEMS){ a = proj_w[e-WQKV_ELEMS]; b = proj_w[e-WQKV_ELEMS+1]; }
  else { a = si_w1[e-WQKV_ELEMS-WPROJ_ELEMS]; b = si_w1[e-WQKV_ELEMS-WPROJ_ELEMS+1]; }
  *(unsigned*)(void*)(wb + e) = cvt2(a, b);
}

// ---------------- K1: QKV GEMM via MFMA, whole B in LDS, 16-row waves, LDS-bounced C-write ----------------
__global__ __launch_bounds__(512, 4) void k_qkv(const float* __restrict__ x1, const float* __restrict__ x2,
                                                const ushortT* __restrict__ wb,
                                                ushortT* __restrict__ q1, ushortT* __restrict__ k2,
                                                ushortT* __restrict__ v1){
  __shared__ char Bs[CC*CC*2];     // 73728 B; reused as C staging after k-loop
  int z = blockIdx.y;
  const float* src = (z == 1) ? x2 : x1;
  ushortT* dst = (z == 0) ? q1 : ((z == 1) ? k2 : v1);
  stage_B512(wb + (size_t)z*CC*CC, Bs);

  int w = threadIdx.x >> 6, l = threadIdx.x & 63;
  int row0 = blockIdx.x*128 + w*16;
  int lr = l & 15;            // frag row (A) / col (B)
  int hk = l >> 4;            // k-phase
  f32x4 acc[12];
  #pragma unroll
  for (int n=0; n<12; n++) acc[n] = (f32x4){0.f,0.f,0.f,0.f};

  const float* ap = src + (size_t)(row0 + lr)*CC + hk*8;
  __syncthreads();

  #pragma unroll
  for (int ks = 0; ks < 6; ks++){
    float4 p0 = *(const float4*)(ap + ks*32);
    float4 p1 = *(const float4*)(ap + ks*32 + 4);
    ABu a;
    a.u[0] = cvt2(p0.x, p0.y); a.u[1] = cvt2(p0.z, p0.w);
    a.u[2] = cvt2(p1.x, p1.y); a.u[3] = cvt2(p1.z, p1.w);
    int kb = ks*64 + hk*16;
    #pragma unroll
    for (int n=0; n<12; n++){
      bf16x8 bfr = ldsB(Bs, n*16 + lr, kb);
      acc[n] = __builtin_amdgcn_mfma_f32_16x16x32_bf16(a.v, bfr, acc[n], 0, 0, 0);
    }
  }
  __syncthreads();   // all waves done reading weights; Bs becomes C staging
  // stage: per-wave region 6400 B; rows padded to 400 B (16B-aligned, bank-shift 16/row)
  char* cbuf = Bs + w*6400;
  int crow = hk*4, ccol = lr;
  #pragma unroll
  for (int n=0; n<12; n++)
    #pragma unroll
    for (int r=0; r<4; r++)
      *(ushortT*)(cbuf + (crow + r)*400 + (n*16 + ccol)*2) = f2b(acc[n][r]);
  // coalesced write-out: 16 rows x 24 uint4 per wave = 6 per lane
  #pragma unroll
  for (int j=0; j<6; j++){
    int c = l + j*64;
    int row = c / 24, kc = c - row*24;
    uint4 v = *(const uint4*)(cbuf + row*400 + kc*16);
    *(uint4*)(void*)(dst + (size_t)(row0 + row)*CC + kc*8) = v;
  }
}

// ---------------- K2: windowed attention via MFMA, staged coalesced output ----------------
template<int HSP, int WSP>
__global__ __launch_bounds__(256, 2) void k_attn(const ushortT* __restrict__ q1, const ushortT* __restrict__ k2,
                                                 const ushortT* __restrict__ v1, const float* __restrict__ pos,
                                                 ushortT* __restrict__ att){
  constexpr int BR = (HSP == 4) ? 0 : 1;
  constexpr int NWH = HH / HSP, NWW = WW / WSP;
  constexpr int CH0 = BR * CBh;
  constexpr float SCALE = 0.20412414523193154f;   // 1/sqrt(24)
  __shared__ ushortT poolA[20480];   // Q [4][64][40]; K @10240; then P [4][64][72]; then O [64][104]
  __shared__ ushortT VTs[9216];      // [4][32][72]
  __shared__ float ps[RTAB*HBn];
  int t = threadIdx.x;
  int wid = blockIdx.x;
  int b = wid / (NWH*NWW);
  int rem = wid - b*(NWH*NWW);
  int wr = rem / NWW, wc = rem - wr*NWW;

  for (int i = t; i < RTAB*HBn; i += 256) ps[i] = pos[(size_t)BR*RTAB*HBn + i];

  #pragma unroll
  for (int it = 0; it < 3; it++){
    int e = t + it*256;                    // 768 = 64 pix * 12 chunks
    int p = e / 12, seg = e - p*12;
    int h = seg / 3, c0 = (seg - h*3)*8;   // 24ch/head = 3 chunks, aligned
    int ii = p / WSP, jj = p - ii*WSP;
    size_t g = ((size_t)b*LL + (size_t)(wr*HSP + ii)*WW + wc*WSP + jj)*CC + CH0 + h*24 + c0;
    uint4 uq = *(const uint4*)(const void*)(q1 + g);
    uint4 uk = *(const uint4*)(const void*)(k2 + g);
    uint4 uv = *(const uint4*)(const void*)(v1 + g);
    *(uint4*)(void*)&poolA[(h*64 + p)*40 + c0] = uq;
    *(uint4*)(void*)&poolA[10240 + (h*64 + p)*40 + c0] = uk;
    union { uint4 u; ushortT s[8]; } vu; vu.u = uv;
    #pragma unroll
    for (int j = 0; j < 8; j++)
      VTs[(h*32 + c0 + j)*72 + p] = vu.s[j];
  }
  {
    int h = t >> 6, p = t & 63;            // zero-pad channels 24..31
    uint4 z4; z4.x = z4.y = z4.z = z4.w = 0u;
    *(uint4*)(void*)&poolA[(h*64 + p)*40 + 24] = z4;
    *(uint4*)(void*)&poolA[10240 + (h*64 + p)*40 + 24] = z4;
  }
  __syncthreads();

  int w = t >> 6, l = t & 63;
  int lo = l & 15, hi = l >> 4;

  bf16x8 qa[4], kb[4];
  #pragma unroll
  for (int mt = 0; mt < 4; mt++)
    qa[mt] = *(const bf16x8*)(const void*)&poolA[(w*64 + mt*16 + lo)*40 + hi*8];
  #pragma unroll
  for (int nt = 0; nt < 4; nt++)
    kb[nt] = *(const bf16x8*)(const void*)&poolA[10240 + (w*64 + nt*16 + lo)*40 + hi*8];
  __syncthreads();   // all frags in regs; poolA becomes P

  f32x4 sacc[4][4];
  #pragma unroll
  for (int mt = 0; mt < 4; mt++)
    #pragma unroll
    for (int nt = 0; nt < 4; nt++) sacc[mt][nt] = (f32x4){0.f,0.f,0.f,0.f};
  #pragma unroll
  for (int mt = 0; mt < 4; mt++)
    #pragma unroll
    for (int nt = 0; nt < 4; nt++)
      sacc[mt][nt] = __builtin_amdgcn_mfma_f32_16x16x32_bf16(qa[mt], kb[nt], sacc[mt][nt], 0, 0, 0);

  float invl[4][4];
  #pragma unroll
  for (int mt = 0; mt < 4; mt++){
    #pragma unroll
    for (int r = 0; r < 4; r++){
      int i = mt*16 + hi*4 + r;
      int i1 = i / WSP, j1 = i - i1*WSP;
      float sv[4];
      #pragma unroll
      for (int nt = 0; nt < 4; nt++){
        int j = nt*16 + lo;
        int i2 = j / WSP, j2 = j - i2*WSP;
        int ridx = (i1 - i2 + HSP - 1)*(2*WSP - 1) + (j1 - j2 + WSP - 1);
        sv[nt] = sacc[mt][nt][r]*SCALE + ps[ridx*HBn + w];
      }
      float mx = fmaxf(fmaxf(sv[0], sv[1]), fmaxf(sv[2], sv[3]));
      #pragma unroll
      for (int off = 1; off < 16; off <<= 1) mx = fmaxf(mx, __shfl_xor(mx, off, 64));
      float sum = 0.f;
      #pragma unroll
      for (int nt = 0; nt < 4; nt++){ sv[nt] = __expf(sv[nt] - mx); sum += sv[nt]; }
      #pragma unroll
      for (int off = 1; off < 16; off <<= 1) sum += __shfl_xor(sum, off, 64);
      invl[mt][r] = 1.0f / sum;
      #pragma unroll
      for (int nt = 0; nt < 4; nt++)
        poolA[(w*64 + i)*72 + nt*16 + lo] = f2b(sv[nt]);
    }
  }
  __syncthreads();

  bf16x8 pa[4][2], vb[2][2];
  #pragma unroll
  for (int mt = 0; mt < 4; mt++)
    #pragma unroll
    for (int kt = 0; kt < 2; kt++)
      pa[mt][kt] = *(const bf16x8*)(const void*)&poolA[(w*64 + mt*16 + lo)*72 + kt*32 + hi*8];
  #pragma unroll
  for (int nt2 = 0; nt2 < 2; nt2++)
    #pragma unroll
    for (int kt = 0; kt < 2; kt++)
      vb[nt2][kt] = *(const bf16x8*)(const void*)&VTs[(w*32 + nt2*16 + lo)*72 + kt*32 + hi*8];
  __syncthreads();   // P fully consumed; poolA becomes output staging

  f32x4 oacc[4][2];
  #pragma unroll
  for (int mt = 0; mt < 4; mt++)
    #pragma unroll
    for (int nt2 = 0; nt2 < 2; nt2++) oacc[mt][nt2] = (f32x4){0.f,0.f,0.f,0.f};
  #pragma unroll
  for (int mt = 0; mt < 4; mt++)
    #pragma unroll
    for (int nt2 = 0; nt2 < 2; nt2++)
      #pragma unroll
      for (int kt = 0; kt < 2; kt++)
        oacc[mt][nt2] = __builtin_amdgcn_mfma_f32_16x16x32_bf16(pa[mt][kt], vb[nt2][kt], oacc[mt][nt2], 0, 0, 0);

  // stage output: [64 pix][104 pad] bf16 (chan = w*24 + d within the 96-half)
  #pragma unroll
  for (int mt = 0; mt < 4; mt++)
    #pragma unroll
    for (int nt2 = 0; nt2 < 2; nt2++){
      int d = nt2*16 + lo;
      if (nt2 == 1 && lo >= 8) continue;   // d >= 24: padded garbage column
      #pragma unroll
      for (int r = 0; r < 4; r++){
        int i = mt*16 + hi*4 + r;
        poolA[i*104 + w*24 + d] = f2b(oacc[mt][nt2][r] * invl[mt][r]);
      }
    }
  __syncthreads();
  // coalesced write: 64 pix x 12 uint4 chunks (96 ch * 2B = 192B contiguous per pixel)
  #pragma unroll
  for (int it = 0; it < 3; it++){
    int c = t + it*256;
    int p = c / 12, seg = c - p*12;
    int ii = p / WSP, jj = p - ii*WSP;
    size_t g = ((size_t)b*LL + (size_t)(wr*HSP + ii)*WW + wc*WSP + jj)*CC + CH0 + seg*8;
    *(uint4*)(void*)(att + g) = *(const uint4*)(const void*)&poolA[p*104 + seg*8];
  }
}

// ---------------- K3: depthwise 3x3 conv + BN + GELU, 8 channels/thread ----------------
__global__ __launch_bounds__(256) void k_conv(const ushortT* __restrict__ v1,
                                              const ushortT* __restrict__ dwt,
                                              const float* __restrict__ cparam,
                                              ushortT* __restrict__ cx){
  int tid = blockIdx.x*256 + threadIdx.x;     // SZ/8 total
  int grp = tid % 24;
  int pix = tid / 24;
  int j = pix & (WW-1);
  int rest = pix >> 7;
  int i = rest & (HH-1);
  int b = rest >> 7;
  int c0 = grp*8;
  uint4 wreg[9];
  #pragma unroll
  for (int k=0;k<9;k++) wreg[k] = *(const uint4*)(const void*)(dwt + k*CC + c0);
  float acc[8];
  #pragma unroll
  for (int t2=0;t2<8;t2++) acc[t2]=0.f;
  #pragma unroll
  for (int ki=0;ki<3;ki++){
    int ii = i + ki - 1;
    if (ii < 0 || ii >= HH) continue;
    #pragma unroll
    for (int kj=0;kj<3;kj++){
      int jj = j + kj - 1;
      if (jj < 0 || jj >= WW) continue;
      uint4 uv = *(const uint4*)(const void*)(v1 + (((size_t)b*LL) + (size_t)ii*WW + jj)*CC + c0);
      float fv[8], fw[8];
      unpack8(uv, fv);
      unpack8(wreg[ki*3+kj], fw);
      #pragma unroll
      for (int t2=0;t2<8;t2++) acc[t2] = fmaf(fv[t2], fw[t2], acc[t2]);
    }
  }
  float4 s0 = *(const float4*)(cparam + c0);
  float4 s1 = *(const float4*)(cparam + c0 + 4);
  float4 o0 = *(const float4*)(cparam + CC + c0);
  float4 o1 = *(const float4*)(cparam + CC + c0 + 4);
  float scv[8] = {s0.x,s0.y,s0.z,s0.w,s1.x,s1.y,s1.z,s1.w};
  float ofv[8] = {o0.x,o0.y,o0.z,o0.w,o1.x,o1.y,o1.z,o1.w};
  unsigned ou[4];
  #pragma unroll
  for (int t2=0;t2<4;t2++){
    float y0 = gelu_exact(acc[2*t2]  *scv[2*t2]   + ofv[2*t2]);
    float y1 = gelu_exact(acc[2*t2+1]*scv[2*t2+1] + ofv[2*t2+1]);
    ou[t2] = pack2(y0, y1);
  }
  uint4 res; res.x=ou[0]; res.y=ou[1]; res.z=ou[2]; res.w=ou[3];
  *(uint4*)(void*)(cx + (size_t)pix*CC + c0) = res;
}

// ---------------- K4: per-pixel SE gate via MFMA ----------------
__global__ __launch_bounds__(256) void k_gate(const ushortT* __restrict__ att,
                                              const ushortT* __restrict__ wsi,
                                              const float* __restrict__ gparam,
                                              const float* __restrict__ si_b2,
                                              float* __restrict__ gate){
  int w = threadIdx.x >> 6, l = threadIdx.x & 63;
  int row0 = blockIdx.x*128 + w*32;
  int lr = l & 15;
  int lk = (l >> 4) * 8;
  f32x4 acc[2][6];
  #pragma unroll
  for (int rt=0; rt<2; rt++)
    #pragma unroll
    for (int n=0; n<6; n++) acc[rt][n] = (f32x4){0.f,0.f,0.f,0.f};
  #pragma unroll
  for (int ks = 0; ks < 6; ks++){
    int k0 = ks*32 + lk;
    bf16x8 a0 = *(const bf16x8*)(const void*)(att + (size_t)(row0 + lr)*CC + k0);
    bf16x8 a1 = *(const bf16x8*)(const void*)(att + (size_t)(row0 + 16 + lr)*CC + k0);
    #pragma unroll
    for (int n=0; n<6; n++){
      bf16x8 bfr = *(const bf16x8*)(const void*)(wsi + (size_t)(n*16 + lr)*CC + k0);
      acc[0][n] = __builtin_amdgcn_mfma_f32_16x16x32_bf16(a0, bfr, acc[0][n], 0, 0, 0);
      acc[1][n] = __builtin_amdgcn_mfma_f32_16x16x32_bf16(a1, bfr, acc[1][n], 0, 0, 0);
    }
  }
  int crow = (l >> 4) * 4, ccol = l & 15;
  float sc6[6], cb6[6], w26[6];
  #pragma unroll
  for (int n=0; n<6; n++){
    int o = n*16 + ccol;
    sc6[n] = gparam[o];
    cb6[n] = gparam[CBh + o];
    w26[n] = gparam[2*CBh + o];
  }
  float sb2 = si_b2[0];
  float ps[2][4];
  #pragma unroll
  for (int rt=0; rt<2; rt++)
    #pragma unroll
    for (int r=0; r<4; r++) ps[rt][r] = 0.f;
  #pragma unroll
  for (int rt=0; rt<2; rt++)
    #pragma unroll
    for (int n=0; n<6; n++)
      #pragma unroll
      for (int r=0; r<4; r++){
        float x = acc[rt][n][r]*sc6[n] + cb6[n];
        ps[rt][r] += gelu_exact(x) * w26[n];
      }
  #pragma unroll
  for (int rt=0; rt<2; rt++)
    #pragma unroll
    for (int r=0; r<4; r++){
      float v = ps[rt][r];
      #pragma unroll
      for (int off = 1; off < 16; off <<= 1) v += __shfl_xor(v, off, 64);
      ps[rt][r] = v;
    }
  if (ccol == 0){
    #pragma unroll
    for (int rt=0; rt<2; rt++)
      #pragma unroll
      for (int r=0; r<4; r++){
        int m = row0 + rt*16 + crow + r;
        gate[m] = 1.0f / (1.0f + __expf(-(ps[rt][r] + sb2)));
      }
  }
}

// ---------------- K5: proj GEMM via MFMA, whole B in LDS, fused gate, LDS-bounced f32 C-write ----------------
__global__ __launch_bounds__(512, 4) void k_proj(const ushortT* __restrict__ att, const ushortT* __restrict__ cx,
                                                 const float* __restrict__ gate,
                                                 const ushortT* __restrict__ wp, const float* __restrict__ pbias,
                                                 float* __restrict__ out){
  __shared__ char Bs[CC*CC*2];     // 73728 B; reused as C staging after k-loop
  stage_B512(wp, Bs);

  int w = threadIdx.x >> 6, l = threadIdx.x & 63;
  int row0 = blockIdx.x*128 + w*16;
  int lr = l & 15;
  int hk = l >> 4;
  float gv = gate[row0 + lr];
  f32x4 acc[12];
  #pragma unroll
  for (int n=0; n<12; n++) acc[n] = (f32x4){0.f,0.f,0.f,0.f};

  size_t base = (size_t)(row0 + lr)*CC + hk*8;
  __syncthreads();

  #pragma unroll
  for (int ks = 0; ks < 6; ks++){
    uint4 ua = *(const uint4*)(const void*)(att + base + ks*32);
    uint4 uc = *(const uint4*)(const void*)(cx  + base + ks*32);
    float fa[8], fc[8];
    unpack8(ua, fa); unpack8(uc, fc);
    #pragma unroll
    for (int j=0;j<8;j++) fa[j] = fmaf(gv, fc[j], fa[j]);
    ABu a;
    a.u[0] = cvt2(fa[0], fa[1]); a.u[1] = cvt2(fa[2], fa[3]);
    a.u[2] = cvt2(fa[4], fa[5]); a.u[3] = cvt2(fa[6], fa[7]);
    int kb = ks*64 + hk*16;
    #pragma unroll
    for (int n=0; n<12; n++){
      bf16x8 bfr = ldsB(Bs, n*16 + lr, kb);
      acc[n] = __builtin_amdgcn_mfma_f32_16x16x32_bf16(a.v, bfr, acc[n], 0, 0, 0);
    }
  }
  __syncthreads();   // weights dead; Bs becomes f32 C staging
  char* cbuf = Bs + w*6400;      // per-wave 16 rows x 400 B (96 f32 + pad)
  int crow = hk*4, ccol = lr;
  #pragma unroll
  for (int half = 0; half < 2; half++){
    #pragma unroll
    for (int n6 = 0; n6 < 6; n6++){
      int n = half*6 + n6;
      float bv = pbias[n*16 + ccol];
      #pragma unroll
      for (int r=0; r<4; r++)
        *(float*)(cbuf + (crow + r)*400 + (n6*16 + ccol)*4) = acc[n][r] + bv;
    }
    #pragma unroll
    for (int j=0; j<6; j++){
      int c = l + j*64;
      int row = c / 24, kc = c - row*24;
      float4 v = *(const float4*)(cbuf + row*400 + kc*16);
      *(float4*)(out + (size_t)(row0 + row)*CC + half*96 + kc*4) = v;
    }
  }
}

extern "C" void kernel_launch(void* const* d_in, const int* in_sizes, int n_in,
                              void* d_out, int out_size, void* d_ws, size_t ws_size,
                              hipStream_t stream){
  const float* x1    = (const float*)d_in[0];
  const float* x2    = (const float*)d_in[1];
  const float* qkv_w = (const float*)d_in[2];
  const float* proj_w= (const float*)d_in[3];
  const float* proj_b= (const float*)d_in[4];
  const float* pw    = (const float*)d_in[5];
  const float* pb    = (const float*)d_in[6];
  const float* g1    = (const float*)d_in[7];
  const float* b1    = (const float*)d_in[8];
  const float* w1    = (const float*)d_in[9];
  const float* c1    = (const float*)d_in[10];
  const float* g2    = (const float*)d_in[11];
  const float* b2    = (const float*)d_in[12];
  const float* w2    = (const float*)d_in[13];
  const float* c2    = (const float*)d_in[14];
  const float* g3    = (const float*)d_in[15];
  const float* b3    = (const float*)d_in[16];
  const float* w3    = (const float*)d_in[17];
  const float* c3    = (const float*)d_in[18];
  const float* dw_w  = (const float*)d_in[19];
  const float* dw_b  = (const float*)d_in[20];
  const float* bn1_g = (const float*)d_in[21];
  const float* bn1_b = (const float*)d_in[22];
  const float* bn1_m = (const float*)d_in[23];
  const float* bn1_v = (const float*)d_in[24];
  const float* si_w1 = (const float*)d_in[25];
  const float* si_b1 = (const float*)d_in[26];
  const float* bn2_g = (const float*)d_in[27];
  const float* bn2_b = (const float*)d_in[28];
  const float* bn2_m = (const float*)d_in[29];
  const float* bn2_v = (const float*)d_in[30];
  const float* si_w2 = (const float*)d_in[31];
  const float* si_b2 = (const float*)d_in[32];
  float* out = (float*)d_out;

  char* ws = (char*)d_ws;
  const size_t SZ  = (size_t)BDIM * LL * CC;   // 25,165,824 elements
  const size_t SZB = SZ * 2;                   // bf16 bytes per buffer
  ushortT* q1   = (ushortT*)(ws);
  ushortT* v1   = (ushortT*)(ws + SZB);
  ushortT* k2   = (ushortT*)(ws + 2*SZB);
  ushortT* att  = (ushortT*)(ws + 3*SZB);
  float*   gate = (float*)  (ws + 4*SZB);
  float*   pos  = (float*)  (ws + 4*SZB + (size_t)BDIM*LL*sizeof(float));
  ushortT* wbf  = (ushortT*)(ws + 4*SZB + (size_t)BDIM*LL*sizeof(float) + 16384);
  ushortT* wproj = wbf + WQKV_ELEMS;
  ushortT* wsi   = wproj + WPROJ_ELEMS;
  float*   gparam = (float*)(wbf + WQKV_ELEMS + WPROJ_ELEMS + WSI_ELEMS);
  float*   cparam = gparam + 3*CBh;
  ushortT* dwt    = (ushortT*)(cparam + 2*CC);
  ushortT* convx = q1;   // q1 dead after attention

  k_pos<<<dim3(2), dim3(256), 0, stream>>>(pw,pb,g1,b1,w1,c1,g2,b2,w2,c2,g3,b3,w3,c3,pos);
  k_cvtw<<<dim3((WALL_PAIRS+255)/256), dim3(256), 0, stream>>>(qkv_w, proj_w, si_w1,
      si_b1, bn2_g, bn2_b, bn2_m, bn2_v, si_w2,
      dw_w, dw_b, bn1_g, bn1_b, bn1_m, bn1_v, wbf, gparam, cparam, dwt);
  k_qkv<<<dim3(1024,3), dim3(512), 0, stream>>>(x1, x2, wbf, q1, k2, v1);
  k_attn<4,16><<<dim3(2048), dim3(256), 0, stream>>>(q1, k2, v1, pos, att);
  k_attn<16,4><<<dim3(2048), dim3(256), 0, stream>>>(q1, k2, v1, pos, att);
  k_conv<<<dim3((unsigned)(SZ/8/256)), dim3(256), 0, stream>>>(v1, dwt, cparam, convx);
  k_gate<<<dim3(1024), dim3(256), 0, stream>>>(att, wsi, gparam, si_b2, gate);
  k_proj<<<dim3(1024), dim3(512), 0, stream>>>(att, convx, gate, wproj, proj_b, out);
}